// Round 5
// baseline (670.109 us; speedup 1.0000x reference)
//
#include <hip/hip_runtime.h>

// ---------------------------------------------------------------------------
// SelfAttentionLayer (talking-heads) on MI355X gfx950. Round 11.
//   * attn v11 = round-6 inner loop VERBATIM (proven 131-134 us; every
//     rescheduling attempt r7/r8/r10 regressed) x 2-way j-split for TLP:
//     grid 512 -> 2 blocks/CU co-resident (r9 measured VGPR=64, LDS=66K:
//     both already permit 2 blocks; only the grid was limiting occupancy).
//     Blocks write partial U (f16) + partial l; r7-proven combine kernel
//     normalizes, applies mix2 + bsum.
//   * XCD decode b=bid&3, s=(bid>>2)&1: each XCD owns one (b, j-half) ->
//     2 MB K/V working set, L2-resident (r7 measured FETCH 76->34 MB).
//   * mix tables + lp live in wf2 region (dead until fc2 cast, which now runs
//     after combine); Up lives in x1 region (dead until out-proj).
//   * everything else unchanged from round 10 (cast_all, transpose_v+bsum,
//     8-phase 256^2 qkv/fc1, 128-tile out-proj/fc2).
// ---------------------------------------------------------------------------

typedef _Float16 f16x8 __attribute__((ext_vector_type(8)));
typedef _Float16 f16x4 __attribute__((ext_vector_type(4)));
typedef _Float16 f16x2 __attribute__((ext_vector_type(2)));
typedef float f32x4 __attribute__((ext_vector_type(4)));

#define B_ 4
#define N_ 1024
#define D_ 1024
#define H_ 16
#define DH_ 64
#define FF_ 4096
#define M_ (B_ * N_)

__device__ __forceinline__ float gelu_act(float x) {
  float z = 0.7978845608028654f * (x + 0.044715f * x * x * x);
  return x / (1.0f + __expf(-2.0f * z));
}

__device__ __forceinline__ void ld_lds16(const _Float16* g, _Float16* l) {
  __builtin_amdgcn_global_load_lds((const __attribute__((address_space(1))) void*)g,
                                   (__attribute__((address_space(3))) void*)l, 16, 0, 0);
}

__device__ __forceinline__ int swz8(int i) {
  return (((i >> 2) << 1) ^ (i & 3)) & 7;
}
// S/P plane addressing (v4/v5-proven): plane p stride 1032 f16, row i (64 f16),
// col j chunk-swizzled. mix1 u16 gathers, b64 writes, b128 PV reads <=2-way.
__device__ __forceinline__ int lds_off(int p, int i, int j) {
  int ch = ((j >> 3) ^ swz8(i) ^ ((p >> 2) << 1)) & 7;
  return p * 1032 + i * 64 + (ch << 3) + (j & 7);
}

// ---------------- fp32 -> fp16 cast (single buffer) ----------------
__global__ __launch_bounds__(256) void cast_f32_f16(const float* __restrict__ in,
                                                    _Float16* __restrict__ out, int n) {
  int i = (blockIdx.x * 256 + threadIdx.x) * 4;
  if (i >= n) return;
  float4 v = *(const float4*)(in + i);
  f16x4 o;
  o[0] = (_Float16)v.x; o[1] = (_Float16)v.y; o[2] = (_Float16)v.z; o[3] = (_Float16)v.w;
  *(f16x4*)(out + i) = o;
}

// ---------------- fused prep: 3 weight casts + mix tables + bsum zero -------
// blocks 0..8191: f32->f16 casts (1024 elts/block). block 8192: tables.
__global__ __launch_bounds__(256) void cast_all(
    const float* __restrict__ a0, _Float16* __restrict__ o0,   // qkv_w  3072*1024
    const float* __restrict__ a1, _Float16* __restrict__ o1,   // out_w  1024*1024
    const float* __restrict__ a2, _Float16* __restrict__ o2,   // fc1_w  4096*1024
    const float* __restrict__ W1, const float* __restrict__ W2,
    _Float16* __restrict__ w1f, _Float16* __restrict__ w2f,
    float* __restrict__ bsum) {
  int b = blockIdx.x, t = threadIdx.x;
  const float* in;
  _Float16* out;
  int base;
  if (b < 3072) { in = a0; out = o0; base = b; }
  else if (b < 4096) { in = a1; out = o1; base = b - 3072; }
  else if (b < 8192) { in = a2; out = o2; base = b - 4096; }
  else {
    w1f[t] = (_Float16)W1[t];
    w2f[t] = (_Float16)W2[t];
    float4 z = {0.f, 0.f, 0.f, 0.f};
    #pragma unroll
    for (int r = 0; r < 4; r++) *(float4*)(bsum + t * 16 + r * 4) = z;
    return;
  }
  int i = (base * 256 + t) * 4;
  float4 v = *(const float4*)(in + i);
  f16x4 o;
  o[0] = (_Float16)v.x; o[1] = (_Float16)v.y; o[2] = (_Float16)v.z; o[3] = (_Float16)v.w;
  *(f16x4*)(out + i) = o;
}

// ---------------- LayerNorm (row of 1024) -> fp16 ----------------
__global__ __launch_bounds__(256) void ln_f16(const float* __restrict__ x,
                                              const float* __restrict__ w,
                                              const float* __restrict__ b,
                                              _Float16* __restrict__ out) {
  int row = blockIdx.x;
  int tid = threadIdx.x;
  const float* xr = x + (size_t)row * D_;
  float4 v = *(const float4*)(xr + tid * 4);
  float s = v.x + v.y + v.z + v.w;
  float sq = v.x * v.x + v.y * v.y + v.z * v.z + v.w * v.w;
  #pragma unroll
  for (int off = 32; off > 0; off >>= 1) {
    s += __shfl_down(s, off);
    sq += __shfl_down(sq, off);
  }
  __shared__ float red[8];
  int wave = tid >> 6, lane = tid & 63;
  if (lane == 0) { red[wave] = s; red[4 + wave] = sq; }
  __syncthreads();
  float ts = red[0] + red[1] + red[2] + red[3];
  float tq = red[4] + red[5] + red[6] + red[7];
  float mean = ts * (1.0f / (float)D_);
  float var = tq * (1.0f / (float)D_) - mean * mean;
  float rs = rsqrtf(var + 1e-5f);
  float4 wv = *(const float4*)(w + tid * 4);
  float4 bv = *(const float4*)(b + tid * 4);
  f16x4 o;
  o[0] = (_Float16)((v.x - mean) * rs * wv.x + bv.x);
  o[1] = (_Float16)((v.y - mean) * rs * wv.y + bv.y);
  o[2] = (_Float16)((v.z - mean) * rs * wv.z + bv.z);
  o[3] = (_Float16)((v.w - mean) * rs * wv.w + bv.w);
  *(f16x4*)(out + (size_t)row * D_ + tid * 4) = o;
}

// ---------------- NT GEMM (128-tile, 2-barrier): for N=1024 shapes ----------------
template <int EPI, int BN, int OCC>
__global__ __launch_bounds__(256, OCC) void gemm_nt(
    const _Float16* __restrict__ A, const _Float16* __restrict__ W,
    const float* __restrict__ bias, int M, int N, int K,
    _Float16* __restrict__ outB, float* __restrict__ outF,
    const float* __restrict__ res, const float* __restrict__ gamma) {
  __shared__ _Float16 As[128 * 64];
  __shared__ _Float16 Bs[BN * 64];
  int tid = threadIdx.x;
  int wave = tid >> 6, lane = tid & 63;
  int quad = lane >> 4, l16 = lane & 15;
  int wm = wave >> 1, wn = wave & 1;
  int m0 = blockIdx.y * 128, n0 = blockIdx.x * BN;
  int lrow = lane >> 3, lcol = (lane & 7) * 8;
  const int NI = (BN == 128) ? 4 : 2;
  const int WN = (BN == 128) ? 64 : 32;

  f32x4 zero = {0.f, 0.f, 0.f, 0.f};
  f32x4 acc[4][NI];
  #pragma unroll
  for (int i = 0; i < 4; i++)
    #pragma unroll
    for (int j = 0; j < NI; j++) acc[i][j] = zero;

  for (int k0 = 0; k0 < K; k0 += 64) {
    __syncthreads();
    #pragma unroll
    for (int c = 0; c < 4; c++) {
      int rb = c * 32 + wave * 8;
      ld_lds16(A + (size_t)(m0 + rb + lrow) * K + k0 + lcol, As + rb * 64);
      if (BN == 128 || c < 2)
        ld_lds16(W + (size_t)(n0 + rb + lrow) * K + k0 + lcol, Bs + rb * 64);
    }
    __syncthreads();
    #pragma unroll
    for (int ks = 0; ks < 2; ks++) {
      int kk = ks * 32 + quad * 8;
      f16x8 a[4], bfr[NI];
      #pragma unroll
      for (int i = 0; i < 4; i++) a[i] = *(const f16x8*)(As + (wm * 64 + i * 16 + l16) * 64 + kk);
      #pragma unroll
      for (int i = 0; i < NI; i++) bfr[i] = *(const f16x8*)(Bs + (wn * WN + i * 16 + l16) * 64 + kk);
      #pragma unroll
      for (int mi = 0; mi < 4; mi++)
        #pragma unroll
        for (int ni = 0; ni < NI; ni++)
          acc[mi][ni] = __builtin_amdgcn_mfma_f32_16x16x32_f16(a[mi], bfr[ni], acc[mi][ni], 0, 0, 0);
    }
  }

  #pragma unroll
  for (int mi = 0; mi < 4; mi++) {
    int grow_base = m0 + wm * 64 + mi * 16 + quad * 4;
    #pragma unroll
    for (int ni = 0; ni < NI; ni++) {
      int gcol = n0 + wn * WN + ni * 16 + l16;
      float bb = bias[gcol];
      float gm = (EPI == 1) ? gamma[gcol] : 0.f;
      #pragma unroll
      for (int r = 0; r < 4; r++) {
        size_t oi = (size_t)(grow_base + r) * N + gcol;
        float c = acc[mi][ni][r] + bb;
        if (EPI == 0) {
          outB[oi] = (_Float16)c;
        } else if (EPI == 1) {
          outF[oi] = res[oi] + gm * c;
        } else {
          outB[oi] = (_Float16)gelu_act(c);
        }
      }
    }
  }
}

// ---------------- 8-phase 256x256 NT GEMM (K=1024, M,N % 256 == 0) ----------------
#define GPH_OPEN()                                      \
  __builtin_amdgcn_sched_barrier(0);                    \
  __builtin_amdgcn_s_barrier();                         \
  asm volatile("s_waitcnt lgkmcnt(0)" ::: "memory");    \
  __builtin_amdgcn_sched_barrier(0);                    \
  __builtin_amdgcn_s_setprio(1)

#define GPH_CLOSE()                                     \
  __builtin_amdgcn_s_setprio(0);                        \
  __builtin_amdgcn_sched_barrier(0);                    \
  __builtin_amdgcn_s_barrier()

#define GPH_CLOSE_VM(n)                                 \
  __builtin_amdgcn_s_setprio(0);                        \
  __builtin_amdgcn_sched_barrier(0);                    \
  asm volatile("s_waitcnt vmcnt(" #n ")" ::: "memory"); \
  __builtin_amdgcn_s_barrier()

#define GMFMA(MB, NB)                                                         \
  _Pragma("unroll") for (int ks = 0; ks < 2; ks++)                            \
  _Pragma("unroll") for (int mi = 0; mi < 4; mi++)                            \
  _Pragma("unroll") for (int ni = 0; ni < 2; ni++)                            \
    acc[MB + mi][NB + ni] = __builtin_amdgcn_mfma_f32_16x16x32_f16(           \
        ar[mi][ks], br[NB + ni][ks], acc[MB + mi][NB + ni], 0, 0, 0)

#define LDA(buf, MB)                                            \
  _Pragma("unroll") for (int ks = 0; ks < 2; ks++)              \
  _Pragma("unroll") for (int mi = 0; mi < 4; mi++)              \
    ar[mi][ks] = rdf(&lds[buf][0][wm][0], MB + mi, ks)

#define LDB(buf, NB)                                            \
  _Pragma("unroll") for (int ks = 0; ks < 2; ks++)              \
  _Pragma("unroll") for (int ni = 0; ni < 2; ni++)              \
    br[NB + ni][ks] = rdf(&lds[buf][1][wn >> 1][0], fbB + NB + ni, ks)

template <int EPI>
__global__ __launch_bounds__(512, 2) void gemm_nt8(
    const _Float16* __restrict__ A, const _Float16* __restrict__ W,
    const float* __restrict__ bias, int M, int N, int K,
    _Float16* __restrict__ outB) {
  __shared__ _Float16 lds[2][2][2][8192];  // [buf][A=0/B=1][row-half][128*64]
  const int tid = threadIdx.x;
  const int wv = tid >> 6, lane = tid & 63;
  const int quad = lane >> 4, l16 = lane & 15;
  const int wm = wv >> 2, wn = wv & 3;
  const int fbB = (wn & 1) * 4;
  const int wg = ((int)blockIdx.x & 7) * ((int)gridDim.x >> 3) + ((int)blockIdx.x >> 3);
  const int m0 = (wg & 15) << 8;   // M/256 == 16 for all uses here
  const int n0 = (wg >> 4) << 8;
  const int gc = ((lane & 7) ^ (lane >> 3)) << 3;
  const int srow = wv * 8 + (lane >> 3);

  auto stageA = [&](int kt, int h) {
    const _Float16* g = A + (size_t)(m0 + h * 128 + srow) * K + kt * 64 + gc;
    _Float16* l = &lds[kt & 1][0][h][wv * 512];
    ld_lds16(g, l);
    ld_lds16(g + (size_t)64 * K, l + 4096);
  };
  auto stageB = [&](int kt, int h) {
    const _Float16* g = W + (size_t)(n0 + h * 128 + srow) * K + kt * 64 + gc;
    _Float16* l = &lds[kt & 1][1][h][wv * 512];
    ld_lds16(g, l);
    ld_lds16(g + (size_t)64 * K, l + 4096);
  };
  auto rdf = [&](const _Float16* base, int fi, int ks) -> f16x8 {
    int row = fi * 16 + l16;
    int pc = ((ks << 2) + quad) ^ (l16 & 7);
    return *(const f16x8*)(base + row * 64 + (pc << 3));
  };

  f32x4 acc[8][4];
  const f32x4 zero = {0.f, 0.f, 0.f, 0.f};
  #pragma unroll
  for (int i = 0; i < 8; i++)
    #pragma unroll
    for (int j = 0; j < 4; j++) acc[i][j] = zero;
  f16x8 ar[4][2], br[4][2];

  stageA(0, 0); stageA(0, 1); stageB(0, 0); stageB(0, 1);
  stageB(1, 0); stageB(1, 1);
  asm volatile("s_waitcnt vmcnt(4)" ::: "memory");
  __builtin_amdgcn_s_barrier();

  const int NT = K >> 6;        // 16
  const int ITERS = NT >> 1;    // 8
  for (int it = 0; it < ITERS - 1; ++it) {
    const int t0 = it * 2;
    LDA(0, 0); LDB(0, 0); stageA(t0 + 1, 0);
    GPH_OPEN(); GMFMA(0, 0); GPH_CLOSE();
    LDB(0, 2); stageA(t0 + 1, 1);
    GPH_OPEN(); GMFMA(0, 2); GPH_CLOSE();
    LDA(0, 4); stageB(t0 + 2, 0);
    GPH_OPEN(); GMFMA(4, 0); GPH_CLOSE();
    stageB(t0 + 2, 1);
    GPH_OPEN(); GMFMA(4, 2); GPH_CLOSE_VM(4);
    LDA(1, 0); LDB(1, 0); stageA(t0 + 2, 0);
    GPH_OPEN(); GMFMA(0, 0); GPH_CLOSE();
    LDB(1, 2); stageA(t0 + 2, 1);
    GPH_OPEN(); GMFMA(0, 2); GPH_CLOSE();
    LDA(1, 4); stageB(t0 + 3, 0);
    GPH_OPEN(); GMFMA(4, 0); GPH_CLOSE();
    stageB(t0 + 3, 1);
    GPH_OPEN(); GMFMA(4, 2); GPH_CLOSE_VM(4);
  }
  {
    LDA(0, 0); LDB(0, 0); stageA(NT - 1, 0);
    GPH_OPEN(); GMFMA(0, 0); GPH_CLOSE();
    LDB(0, 2); stageA(NT - 1, 1);
    GPH_OPEN(); GMFMA(0, 2); GPH_CLOSE();
    LDA(0, 4);
    GPH_OPEN(); GMFMA(4, 0); GPH_CLOSE();
    GPH_OPEN(); GMFMA(4, 2); GPH_CLOSE_VM(0);
    LDA(1, 0); LDB(1, 0);
    GPH_OPEN(); GMFMA(0, 0); GPH_CLOSE();
    LDB(1, 2);
    GPH_OPEN(); GMFMA(0, 2); GPH_CLOSE();
    LDA(1, 4);
    GPH_OPEN(); GMFMA(4, 0); GPH_CLOSE();
    GPH_OPEN(); GMFMA(4, 2); GPH_CLOSE();
  }

  #pragma unroll
  for (int mi = 0; mi < 8; mi++) {
    int grow = m0 + wm * 128 + mi * 16 + quad * 4;
    #pragma unroll
    for (int ni = 0; ni < 4; ni++) {
      int gcol = n0 + wn * 64 + ni * 16 + l16;
      float bb = bias[gcol];
      #pragma unroll
      for (int r = 0; r < 4; r++) {
        size_t oi = (size_t)(grow + r) * N + gcol;
        float c = acc[mi][ni][r] + bb;
        outB[oi] = (_Float16)(EPI == 2 ? gelu_act(c) : c);
      }
    }
  }
}

// ---------------- V transpose + bsum accumulation ----------------
// vt[b][h][d][j]; also bsum[b][h*64+d] += b2[h] * sum_j V[b,h,j,d]
__global__ __launch_bounds__(256) void transpose_v(const _Float16* __restrict__ qkv,
                                                   _Float16* __restrict__ vt,
                                                   const float* __restrict__ b2,
                                                   float* __restrict__ bsum) {
  int jt = blockIdx.x;
  int h = blockIdx.y;
  int b = blockIdx.z;
  __shared__ _Float16 tl[64][68];
  int tid = threadIdx.x;
  int j0 = jt * 64;
  #pragma unroll
  for (int k = 0; k < 16; k++) {
    int idx = k * 256 + tid;
    int jr = idx >> 6, dc = idx & 63;
    tl[jr][dc] = qkv[(size_t)(b * N_ + j0 + jr) * (3 * D_) + 2 * D_ + h * 64 + dc];
  }
  __syncthreads();
  #pragma unroll
  for (int k = 0; k < 16; k++) {
    int idx = k * 256 + tid;
    int dr = idx >> 6, jc = idx & 63;
    vt[(size_t)((b * H_ + h) * DH_ + dr) * N_ + j0 + jc] = tl[jc][dr];
  }
  int d = tid & 63, jq = tid >> 6;
  float s = 0.f;
  #pragma unroll
  for (int r = 0; r < 16; r++) s += (float)tl[jq * 16 + r][d];
  atomicAdd(&bsum[b * D_ + h * 64 + d], b2[h] * s);
}

// ---------------- Talking-heads attention, v11: r6 loop x j-split ----------------
// grid 512: b = bid&3, s = (bid>>2)&1, i-tile = bid>>3. XCD = bid%8 = b+4s
// owns a 2 MB K/V working set (L2-resident). 16 waves; wave meaning:
// computeS: head h=wave; mix1: row i=wave; PV: mixed-head e=wave.
// Writes partial U (f16) + partial l (f32); combine kernel finishes.
__global__ __launch_bounds__(1024, 8) void attn_th(
    const _Float16* __restrict__ qkv, const _Float16* __restrict__ vt,
    const _Float16* __restrict__ w1f, const float* __restrict__ b1f,
    _Float16* __restrict__ Up, float* __restrict__ lp) {
  __shared__ __align__(16) _Float16 SP[2 * 16512];  // S planes | P planes
  _Float16* Sp = SP;
  _Float16* Pp = SP + 16512;

  const int tid = threadIdx.x;
  const int wave = tid >> 6;
  const int lane = tid & 63;
  const int quad = lane >> 4, l16 = lane & 15;
  const int bid = blockIdx.x;
  const int b = bid & 3;
  const int s = (bid >> 2) & 1;
  const int i0 = (bid >> 3) << 4;
  const size_t bN = (size_t)b * N_;
  const f32x4 zero = {0.f, 0.f, 0.f, 0.f};

  // Q fragments (head=wave), pre-scaled by DH^-1/2 = 0.125 (exact in f16)
  f16x8 qf[2];
  #pragma unroll
  for (int ks = 0; ks < 2; ks++) {
    f16x8 q = *(const f16x8*)(qkv + (bN + i0 + l16) * 3072 + wave * 64 + ks * 32 + quad * 8);
    #pragma unroll
    for (int e = 0; e < 8; e++) q[e] = q[e] * (_Float16)0.125f;
    qf[ks] = q;
  }
  // W1 B-fragment: B[k=h][n=e] = W1[e][h]
  f16x4 w1a = *(const f16x4*)(w1f + l16 * 16 + quad * 4);
  float b1v = b1f[l16];
  f32x4 b1i = {b1v, b1v, b1v, b1v};

  const _Float16* vbase = vt + (size_t)((b * H_ + wave) * DH_ + l16) * N_ + quad * 8;

  f32x4 uacc[4];
  #pragma unroll
  for (int nt = 0; nt < 4; nt++) uacc[nt] = zero;
  float lacc = 0.f;

  // K fragments for the current tile (reloaded in place each iteration)
  f16x8 kcur[4][2];
  auto loadK = [&](int j0) {
    #pragma unroll
    for (int jb = 0; jb < 4; jb++) {
      const _Float16* kb = qkv + (bN + j0 + jb * 16 + l16) * 3072 + 1024 + wave * 64 + quad * 8;
      kcur[jb][0] = *(const f16x8*)kb;
      kcur[jb][1] = *(const f16x8*)(kb + 32);
    }
  };
  const int sbase = s << 9;  // 512-key half
  loadK(sbase);

  f16x8 vreg[4];  // first 32-j half of V tile, prefetched

  for (int t = 0; t < 8; t++) {
    int j0 = sbase + t * 64;
    // ---- S = (QK^T)^T for head h=wave: C[m=j][n=i] -> S plane [h][i][j]
    f32x4 sres[4];
    #pragma unroll
    for (int jb = 0; jb < 4; jb++) {
      f32x4 sr = __builtin_amdgcn_mfma_f32_16x16x32_f16(kcur[jb][0], qf[0], zero, 0, 0, 0);
      sres[jb] = __builtin_amdgcn_mfma_f32_16x16x32_f16(kcur[jb][1], qf[1], sr, 0, 0, 0);
    }
    #pragma unroll
    for (int jb = 0; jb < 4; jb++) {
      f16x4 sv;
      #pragma unroll
      for (int r = 0; r < 4; r++) sv[r] = (_Float16)sres[jb][r];
      *(f16x4*)(Sp + lds_off(wave, l16, jb * 16 + quad * 4)) = sv;
    }
    // ---- prefetch next K tile (kcur dead after the MFMAs above) and this
    // tile's first V half; the barrier's vmcnt(0) drain makes them resident.
    if (t < 7) loadK(j0 + 64);
    #pragma unroll
    for (int nt = 0; nt < 4; nt++)
      vreg[nt] = *(const f16x8*)(vbase + (size_t)(nt * 16) * N_ + j0);
    __syncthreads();
    // ---- mix1 (row i=wave) -> exp (unnormalized) -> P planes + l accumulate
    #pragma unroll
    for (int cg = 0; cg < 4; cg++) {
      f16x4 sf;
      #pragma unroll
      for (int t4 = 0; t4 < 4; t4++)
        sf[t4] = Sp[lds_off(quad * 4 + t4, wave, cg * 16 + l16)];
      f32x4 a = __builtin_amdgcn_mfma_f32_16x16x16f16(sf, w1a, b1i, 0, 0, 0);
      f16x4 pv;
      #pragma unroll
      for (int r = 0; r < 4; r++) {
        float e = __expf(a[r]);
        lacc += e;
        pv[r] = (_Float16)e;
      }
      *(f16x4*)(Pp + lds_off(l16, wave, cg * 16 + quad * 4)) = pv;
    }
    __syncthreads();
    // ---- PV: U_e += V @ P_e^T (e=wave): C[m=d][n=i]
    f16x8 pf0 = *(const f16x8*)(Pp + lds_off(wave, l16, quad * 8));
    f16x8 pf1 = *(const f16x8*)(Pp + lds_off(wave, l16, 32 + quad * 8));
    #pragma unroll
    for (int nt = 0; nt < 4; nt++)
      uacc[nt] = __builtin_amdgcn_mfma_f32_16x16x32_f16(vreg[nt], pf0, uacc[nt], 0, 0, 0);
    #pragma unroll
    for (int nt = 0; nt < 4; nt++) {
      f16x8 vf = *(const f16x8*)(vbase + (size_t)(nt * 16) * N_ + j0 + 32);
      uacc[nt] = __builtin_amdgcn_mfma_f32_16x16x32_f16(vf, pf1, uacc[nt], 0, 0, 0);
    }
    // no barrier: next computeS writes S planes (disjoint from P); mix1(t+1)
    // writes P only after the next barrier.
  }

  // ---- epilogue: partial l (per e=l16, i=wave) + partial U to global ----
  lacc += __shfl_xor(lacc, 16);
  lacc += __shfl_xor(lacc, 32);
  if (quad == 0) lp[(((size_t)s * B_ + b) * H_ + l16) * N_ + i0 + wave] = lacc;
  const size_t ub = ((((size_t)s * B_ + b) * H_ + wave) * N_ + i0 + l16) * 64;
  #pragma unroll
  for (int nt = 0; nt < 4; nt++) {
    f16x4 u;
    #pragma unroll
    for (int r = 0; r < 4; r++) u[r] = (_Float16)uacc[nt][r];
    *(f16x4*)(Up + ub + nt * 16 + quad * 4) = u;
  }
}

// ---------------- combine: Un=(U0+U1)/(l0+l1); ob = W2@Un + bsum ----------------
// grid (64 i-tiles, 4 b), 256 thr (r7-proven).
__global__ __launch_bounds__(256) void attn_combine(
    const _Float16* __restrict__ Up, const float* __restrict__ lp,
    const _Float16* __restrict__ w2f, const float* __restrict__ bsum,
    _Float16* __restrict__ ob) {
  const int i0 = blockIdx.x * 16;
  const int b = blockIdx.y;
  const int t = threadIdx.x;
  __shared__ float w2s[256];
  __shared__ float linv[16][17];
  {
    int e = t >> 4, il = t & 15;
    float l0 = lp[((size_t)(0 * B_ + b) * H_ + e) * N_ + i0 + il];
    float l1 = lp[((size_t)(1 * B_ + b) * H_ + e) * N_ + i0 + il];
    linv[e][il] = 1.0f / (l0 + l1);
    w2s[t] = (float)w2f[t];
  }
  __syncthreads();
  const int il = t >> 4, dg = (t & 15) * 4;
  const size_t s1off = (size_t)B_ * H_ * N_ * 64;
  float o[16][4];
  #pragma unroll
  for (int g = 0; g < 16; g++)
    #pragma unroll
    for (int r = 0; r < 4; r++) o[g][r] = 0.f;
  for (int e = 0; e < 16; e++) {
    size_t ubr = (((size_t)b * H_ + e) * N_ + i0 + il) * 64 + dg;
    f16x4 u0 = *(const f16x4*)(Up + ubr);
    f16x4 u1 = *(const f16x4*)(Up + s1off + ubr);
    float li = linv[e][il];
    float un[4];
    #pragma unroll
    for (int r = 0; r < 4; r++) un[r] = ((float)u0[r] + (float)u1[r]) * li;
    #pragma unroll
    for (int g = 0; g < 16; g++) {
      float w = w2s[g * 16 + e];
      #pragma unroll
      for (int r = 0; r < 4; r++) o[g][r] += w * un[r];
    }
  }
  const size_t rowbase = ((size_t)b * N_ + i0 + il) * D_;
  #pragma unroll
  for (int g = 0; g < 16; g++) {
    f32x4 bs = *(const f32x4*)(bsum + b * D_ + g * 64 + dg);
    f16x4 ov;
    #pragma unroll
    for (int r = 0; r < 4; r++) ov[r] = (_Float16)(o[g][r] + bs[r]);
    *(f16x4*)(ob + rowbase + g * 64 + dg) = ov;
  }
}

// ---------------------------------------------------------------------------
extern "C" void kernel_launch(void* const* d_in, const int* in_sizes, int n_in,
                              void* d_out, int out_size, void* d_ws, size_t ws_size,
                              hipStream_t stream) {
  const float* x      = (const float*)d_in[0];
  const float* ln1_w  = (const float*)d_in[1];
  const float* ln1_b  = (const float*)d_in[2];
  const float* qkv_w  = (const float*)d_in[3];
  const float* qkv_b  = (const float*)d_in[4];
  const float* plw    = (const float*)d_in[5];
  const float* plb    = (const float*)d_in[6];
  const float* pww    = (const float*)d_in[7];
  const float* pwb    = (const float*)d_in[8];
  const float* out_w  = (const float*)d_in[9];
  const float* out_b  = (const float*)d_in[10];
  const float* gamma1 = (const float*)d_in[11];
  const float* ln2_w  = (const float*)d_in[12];
  const float* ln2_b  = (const float*)d_in[13];
  const float* fc1_w  = (const float*)d_in[14];
  const float* fc1_b  = (const float*)d_in[15];
  const float* fc2_w  = (const float*)d_in[16];
  const float* fc2_b  = (const float*)d_in[17];
  const float* gamma2 = (const float*)d_in[18];
  float* out = (float*)d_out;

  char* ws = (char*)d_ws;
  _Float16* wq   = (_Float16*)(ws + 0);          // 6291456 B
  _Float16* wo   = (_Float16*)(ws + 6291456);    // 2097152 B
  _Float16* wf1  = (_Float16*)(ws + 8388608);    // 8388608 B (clean fc1 weights)
  _Float16* wf2  = (_Float16*)(ws + 16777216);   // 8388608 B (hosts mix tables + lp
                                                 //  during attn; fc2 cast after combine)
  float*    x1   = (float*)   (ws + 25165824);   // 16777216 B (hosts Up during attn;
                                                 //  written by out-proj after combine)
  _Float16* ob   = (_Float16*)(ws + 41943040);   // 8388608 B
  _Float16* hb   = (_Float16*)(ws + 50331648);   // 8388608 B
  _Float16* qkvb = (_Float16*)(ws + 58720256);   // 25165824 B
  _Float16* vtb  = (_Float16*)(ws + 83886080);   // 8388608 B
  _Float16* fb   = (_Float16*)(ws + 58720256);   // 33554432 B, aliases qkvb+vtb (dead by then)
  _Float16* w1f  = (_Float16*)(ws + 16777216);          // 512 B
  _Float16* w2f  = (_Float16*)(ws + 16777216 + 512);    // 512 B
  float*    bsum = (float*)   (ws + 16777216 + 1024);   // 16384 B
  float*    lp   = (float*)   (ws + 16777216 + 17408);  // 524288 B
  _Float16* Up   = (_Float16*)(ws + 25165824);          // 16777216 B
  if (ws_size < 92274688) return;

  cast_all<<<8193, 256, 0, stream>>>(qkv_w, wq, out_w, wo, fc1_w, wf1,
                                     plw, pww, w1f, w2f, bsum);

  ln_f16<<<4096, 256, 0, stream>>>(x, ln1_w, ln1_b, hb);
  gemm_nt8<0><<<192, 512, 0, stream>>>(hb, wq, qkv_b, M_, 3 * D_, D_, qkvb);
  transpose_v<<<dim3(16, 16, 4), 256, 0, stream>>>(qkvb, vtb, pwb, bsum);
  attn_th<<<512, 1024, 0, stream>>>(qkvb, vtb, w1f, plb, Up, lp);
  attn_combine<<<dim3(64, 4), 256, 0, stream>>>(Up, lp, w2f, bsum, ob);
  cast_f32_f16<<<4096, 256, 0, stream>>>(fc2_w, wf2, 4096 * 1024);
  gemm_nt<1, 64, 4><<<dim3(16, 32), 256, 0, stream>>>(ob, wo, out_b, M_, D_, D_, nullptr, x1, x, gamma1);

  ln_f16<<<4096, 256, 0, stream>>>(x1, ln2_w, ln2_b, hb);
  gemm_nt8<2><<<256, 512, 0, stream>>>(hb, wf1, fc1_b, M_, FF_, D_, fb);
  gemm_nt<1, 64, 4><<<dim3(16, 32), 256, 0, stream>>>(fb, wf2, fc2_b, M_, D_, FF_, nullptr, out, x1, gamma2);
}

// Round 6
// 449.904 us; speedup vs baseline: 1.4895x; 1.4895x over previous
//
#include <hip/hip_runtime.h>

// ---------------------------------------------------------------------------
// SelfAttentionLayer (talking-heads) on MI355X gfx950. Round 12.
// CONSOLIDATION: best measured variant of every kernel.
//   * attn_th = round-6/9 version VERBATIM (131-134 us, 1 blk/CU, full ILP).
//     Closed arc: r7 thin-regs=146, r8 no-drain=145, r10 covered-issue=160,
//     r11 j-split@8waves/EU=330 (VGPR cap 64 < ~130 demand -> scratch spill,
//     1.26 GB spill traffic). The r6 interleave is the local optimum.
//   * cast_all fused prep (4 weight casts + mix tables + bsum zero) [r10 win].
//   * transpose_v + bsum column-sum fusion [r10 win].
//   * qkv/fc1 on 8-phase 256^2 schedule [r9 win].
//   * out-proj/fc2 on 128x64-tile gemm_nt (prior-session-tuned BN=64/OCC=4).
// ---------------------------------------------------------------------------

typedef _Float16 f16x8 __attribute__((ext_vector_type(8)));
typedef _Float16 f16x4 __attribute__((ext_vector_type(4)));
typedef _Float16 f16x2 __attribute__((ext_vector_type(2)));
typedef float f32x4 __attribute__((ext_vector_type(4)));

#define B_ 4
#define N_ 1024
#define D_ 1024
#define H_ 16
#define DH_ 64
#define FF_ 4096
#define M_ (B_ * N_)

__device__ __forceinline__ float gelu_act(float x) {
  float z = 0.7978845608028654f * (x + 0.044715f * x * x * x);
  return x / (1.0f + __expf(-2.0f * z));
}

__device__ __forceinline__ void ld_lds16(const _Float16* g, _Float16* l) {
  __builtin_amdgcn_global_load_lds((const __attribute__((address_space(1))) void*)g,
                                   (__attribute__((address_space(3))) void*)l, 16, 0, 0);
}

__device__ __forceinline__ int swz8(int i) {
  return (((i >> 2) << 1) ^ (i & 3)) & 7;
}
// S/P plane addressing (v4/v5-proven): plane p stride 1032 f16, row i (64 f16),
// col j chunk-swizzled. mix1 u16 gathers, b64 writes, b128 PV reads <=2-way.
__device__ __forceinline__ int lds_off(int p, int i, int j) {
  int ch = ((j >> 3) ^ swz8(i) ^ ((p >> 2) << 1)) & 7;
  return p * 1032 + i * 64 + (ch << 3) + (j & 7);
}

// ---------------- fused prep: 4 weight casts + mix tables + bsum zero -------
// blocks 0..12287: f32->f16 casts (1024 elts/block). block 12288: tables.
__global__ __launch_bounds__(256) void cast_all(
    const float* __restrict__ a0, _Float16* __restrict__ o0,   // qkv_w  3072*1024
    const float* __restrict__ a1, _Float16* __restrict__ o1,   // out_w  1024*1024
    const float* __restrict__ a2, _Float16* __restrict__ o2,   // fc1_w  4096*1024
    const float* __restrict__ a3, _Float16* __restrict__ o3,   // fc2_w  1024*4096
    const float* __restrict__ W1, const float* __restrict__ W2,
    _Float16* __restrict__ w1f, _Float16* __restrict__ w2f,
    float* __restrict__ bsum) {
  int b = blockIdx.x, t = threadIdx.x;
  const float* in;
  _Float16* out;
  int base;
  if (b < 3072) { in = a0; out = o0; base = b; }
  else if (b < 4096) { in = a1; out = o1; base = b - 3072; }
  else if (b < 8192) { in = a2; out = o2; base = b - 4096; }
  else if (b < 12288) { in = a3; out = o3; base = b - 8192; }
  else {
    w1f[t] = (_Float16)W1[t];
    w2f[t] = (_Float16)W2[t];
    float4 z = {0.f, 0.f, 0.f, 0.f};
    #pragma unroll
    for (int r = 0; r < 4; r++) *(float4*)(bsum + t * 16 + r * 4) = z;
    return;
  }
  int i = (base * 256 + t) * 4;
  float4 v = *(const float4*)(in + i);
  f16x4 o;
  o[0] = (_Float16)v.x; o[1] = (_Float16)v.y; o[2] = (_Float16)v.z; o[3] = (_Float16)v.w;
  *(f16x4*)(out + i) = o;
}

// ---------------- LayerNorm (row of 1024) -> fp16 ----------------
__global__ __launch_bounds__(256) void ln_f16(const float* __restrict__ x,
                                              const float* __restrict__ w,
                                              const float* __restrict__ b,
                                              _Float16* __restrict__ out) {
  int row = blockIdx.x;
  int tid = threadIdx.x;
  const float* xr = x + (size_t)row * D_;
  float4 v = *(const float4*)(xr + tid * 4);
  float s = v.x + v.y + v.z + v.w;
  float sq = v.x * v.x + v.y * v.y + v.z * v.z + v.w * v.w;
  #pragma unroll
  for (int off = 32; off > 0; off >>= 1) {
    s += __shfl_down(s, off);
    sq += __shfl_down(sq, off);
  }
  __shared__ float red[8];
  int wave = tid >> 6, lane = tid & 63;
  if (lane == 0) { red[wave] = s; red[4 + wave] = sq; }
  __syncthreads();
  float ts = red[0] + red[1] + red[2] + red[3];
  float tq = red[4] + red[5] + red[6] + red[7];
  float mean = ts * (1.0f / (float)D_);
  float var = tq * (1.0f / (float)D_) - mean * mean;
  float rs = rsqrtf(var + 1e-5f);
  float4 wv = *(const float4*)(w + tid * 4);
  float4 bv = *(const float4*)(b + tid * 4);
  f16x4 o;
  o[0] = (_Float16)((v.x - mean) * rs * wv.x + bv.x);
  o[1] = (_Float16)((v.y - mean) * rs * wv.y + bv.y);
  o[2] = (_Float16)((v.z - mean) * rs * wv.z + bv.z);
  o[3] = (_Float16)((v.w - mean) * rs * wv.w + bv.w);
  *(f16x4*)(out + (size_t)row * D_ + tid * 4) = o;
}

// ---------------- NT GEMM (128-tile, 2-barrier): for N=1024 shapes ----------------
template <int EPI, int BN, int OCC>
__global__ __launch_bounds__(256, OCC) void gemm_nt(
    const _Float16* __restrict__ A, const _Float16* __restrict__ W,
    const float* __restrict__ bias, int M, int N, int K,
    _Float16* __restrict__ outB, float* __restrict__ outF,
    const float* __restrict__ res, const float* __restrict__ gamma) {
  __shared__ _Float16 As[128 * 64];
  __shared__ _Float16 Bs[BN * 64];
  int tid = threadIdx.x;
  int wave = tid >> 6, lane = tid & 63;
  int quad = lane >> 4, l16 = lane & 15;
  int wm = wave >> 1, wn = wave & 1;
  int m0 = blockIdx.y * 128, n0 = blockIdx.x * BN;
  int lrow = lane >> 3, lcol = (lane & 7) * 8;
  const int NI = (BN == 128) ? 4 : 2;
  const int WN = (BN == 128) ? 64 : 32;

  f32x4 zero = {0.f, 0.f, 0.f, 0.f};
  f32x4 acc[4][NI];
  #pragma unroll
  for (int i = 0; i < 4; i++)
    #pragma unroll
    for (int j = 0; j < NI; j++) acc[i][j] = zero;

  for (int k0 = 0; k0 < K; k0 += 64) {
    __syncthreads();
    #pragma unroll
    for (int c = 0; c < 4; c++) {
      int rb = c * 32 + wave * 8;
      ld_lds16(A + (size_t)(m0 + rb + lrow) * K + k0 + lcol, As + rb * 64);
      if (BN == 128 || c < 2)
        ld_lds16(W + (size_t)(n0 + rb + lrow) * K + k0 + lcol, Bs + rb * 64);
    }
    __syncthreads();
    #pragma unroll
    for (int ks = 0; ks < 2; ks++) {
      int kk = ks * 32 + quad * 8;
      f16x8 a[4], bfr[NI];
      #pragma unroll
      for (int i = 0; i < 4; i++) a[i] = *(const f16x8*)(As + (wm * 64 + i * 16 + l16) * 64 + kk);
      #pragma unroll
      for (int i = 0; i < NI; i++) bfr[i] = *(const f16x8*)(Bs + (wn * WN + i * 16 + l16) * 64 + kk);
      #pragma unroll
      for (int mi = 0; mi < 4; mi++)
        #pragma unroll
        for (int ni = 0; ni < NI; ni++)
          acc[mi][ni] = __builtin_amdgcn_mfma_f32_16x16x32_f16(a[mi], bfr[ni], acc[mi][ni], 0, 0, 0);
    }
  }

  #pragma unroll
  for (int mi = 0; mi < 4; mi++) {
    int grow_base = m0 + wm * 64 + mi * 16 + quad * 4;
    #pragma unroll
    for (int ni = 0; ni < NI; ni++) {
      int gcol = n0 + wn * WN + ni * 16 + l16;
      float bb = bias[gcol];
      float gm = (EPI == 1) ? gamma[gcol] : 0.f;
      #pragma unroll
      for (int r = 0; r < 4; r++) {
        size_t oi = (size_t)(grow_base + r) * N + gcol;
        float c = acc[mi][ni][r] + bb;
        if (EPI == 0) {
          outB[oi] = (_Float16)c;
        } else if (EPI == 1) {
          outF[oi] = res[oi] + gm * c;
        } else {
          outB[oi] = (_Float16)gelu_act(c);
        }
      }
    }
  }
}

// ---------------- 8-phase 256x256 NT GEMM (K=1024, M,N % 256 == 0) ----------------
#define GPH_OPEN()                                      \
  __builtin_amdgcn_sched_barrier(0);                    \
  __builtin_amdgcn_s_barrier();                         \
  asm volatile("s_waitcnt lgkmcnt(0)" ::: "memory");    \
  __builtin_amdgcn_sched_barrier(0);                    \
  __builtin_amdgcn_s_setprio(1)

#define GPH_CLOSE()                                     \
  __builtin_amdgcn_s_setprio(0);                        \
  __builtin_amdgcn_sched_barrier(0);                    \
  __builtin_amdgcn_s_barrier()

#define GPH_CLOSE_VM(n)                                 \
  __builtin_amdgcn_s_setprio(0);                        \
  __builtin_amdgcn_sched_barrier(0);                    \
  asm volatile("s_waitcnt vmcnt(" #n ")" ::: "memory"); \
  __builtin_amdgcn_s_barrier()

#define GMFMA(MB, NB)                                                         \
  _Pragma("unroll") for (int ks = 0; ks < 2; ks++)                            \
  _Pragma("unroll") for (int mi = 0; mi < 4; mi++)                            \
  _Pragma("unroll") for (int ni = 0; ni < 2; ni++)                            \
    acc[MB + mi][NB + ni] = __builtin_amdgcn_mfma_f32_16x16x32_f16(           \
        ar[mi][ks], br[NB + ni][ks], acc[MB + mi][NB + ni], 0, 0, 0)

#define LDA(buf, MB)                                            \
  _Pragma("unroll") for (int ks = 0; ks < 2; ks++)              \
  _Pragma("unroll") for (int mi = 0; mi < 4; mi++)              \
    ar[mi][ks] = rdf(&lds[buf][0][wm][0], MB + mi, ks)

#define LDB(buf, NB)                                            \
  _Pragma("unroll") for (int ks = 0; ks < 2; ks++)              \
  _Pragma("unroll") for (int ni = 0; ni < 2; ni++)              \
    br[NB + ni][ks] = rdf(&lds[buf][1][wn >> 1][0], fbB + NB + ni, ks)

template <int EPI>
__global__ __launch_bounds__(512, 2) void gemm_nt8(
    const _Float16* __restrict__ A, const _Float16* __restrict__ W,
    const float* __restrict__ bias, int M, int N, int K,
    _Float16* __restrict__ outB) {
  __shared__ _Float16 lds[2][2][2][8192];  // [buf][A=0/B=1][row-half][128*64]
  const int tid = threadIdx.x;
  const int wv = tid >> 6, lane = tid & 63;
  const int quad = lane >> 4, l16 = lane & 15;
  const int wm = wv >> 2, wn = wv & 3;
  const int fbB = (wn & 1) * 4;
  const int wg = ((int)blockIdx.x & 7) * ((int)gridDim.x >> 3) + ((int)blockIdx.x >> 3);
  const int m0 = (wg & 15) << 8;   // M/256 == 16 for all uses here
  const int n0 = (wg >> 4) << 8;
  const int gc = ((lane & 7) ^ (lane >> 3)) << 3;
  const int srow = wv * 8 + (lane >> 3);

  auto stageA = [&](int kt, int h) {
    const _Float16* g = A + (size_t)(m0 + h * 128 + srow) * K + kt * 64 + gc;
    _Float16* l = &lds[kt & 1][0][h][wv * 512];
    ld_lds16(g, l);
    ld_lds16(g + (size_t)64 * K, l + 4096);
  };
  auto stageB = [&](int kt, int h) {
    const _Float16* g = W + (size_t)(n0 + h * 128 + srow) * K + kt * 64 + gc;
    _Float16* l = &lds[kt & 1][1][h][wv * 512];
    ld_lds16(g, l);
    ld_lds16(g + (size_t)64 * K, l + 4096);
  };
  auto rdf = [&](const _Float16* base, int fi, int ks) -> f16x8 {
    int row = fi * 16 + l16;
    int pc = ((ks << 2) + quad) ^ (l16 & 7);
    return *(const f16x8*)(base + row * 64 + (pc << 3));
  };

  f32x4 acc[8][4];
  const f32x4 zero = {0.f, 0.f, 0.f, 0.f};
  #pragma unroll
  for (int i = 0; i < 8; i++)
    #pragma unroll
    for (int j = 0; j < 4; j++) acc[i][j] = zero;
  f16x8 ar[4][2], br[4][2];

  stageA(0, 0); stageA(0, 1); stageB(0, 0); stageB(0, 1);
  stageB(1, 0); stageB(1, 1);
  asm volatile("s_waitcnt vmcnt(4)" ::: "memory");
  __builtin_amdgcn_s_barrier();

  const int NT = K >> 6;        // 16
  const int ITERS = NT >> 1;    // 8
  for (int it = 0; it < ITERS - 1; ++it) {
    const int t0 = it * 2;
    LDA(0, 0); LDB(0, 0); stageA(t0 + 1, 0);
    GPH_OPEN(); GMFMA(0, 0); GPH_CLOSE();
    LDB(0, 2); stageA(t0 + 1, 1);
    GPH_OPEN(); GMFMA(0, 2); GPH_CLOSE();
    LDA(0, 4); stageB(t0 + 2, 0);
    GPH_OPEN(); GMFMA(4, 0); GPH_CLOSE();
    stageB(t0 + 2, 1);
    GPH_OPEN(); GMFMA(4, 2); GPH_CLOSE_VM(4);
    LDA(1, 0); LDB(1, 0); stageA(t0 + 2, 0);
    GPH_OPEN(); GMFMA(0, 0); GPH_CLOSE();
    LDB(1, 2); stageA(t0 + 2, 1);
    GPH_OPEN(); GMFMA(0, 2); GPH_CLOSE();
    LDA(1, 4); stageB(t0 + 3, 0);
    GPH_OPEN(); GMFMA(4, 0); GPH_CLOSE();
    stageB(t0 + 3, 1);
    GPH_OPEN(); GMFMA(4, 2); GPH_CLOSE_VM(4);
  }
  {
    LDA(0, 0); LDB(0, 0); stageA(NT - 1, 0);
    GPH_OPEN(); GMFMA(0, 0); GPH_CLOSE();
    LDB(0, 2); stageA(NT - 1, 1);
    GPH_OPEN(); GMFMA(0, 2); GPH_CLOSE();
    LDA(0, 4);
    GPH_OPEN(); GMFMA(4, 0); GPH_CLOSE();
    GPH_OPEN(); GMFMA(4, 2); GPH_CLOSE_VM(0);
    LDA(1, 0); LDB(1, 0);
    GPH_OPEN(); GMFMA(0, 0); GPH_CLOSE();
    LDB(1, 2);
    GPH_OPEN(); GMFMA(0, 2); GPH_CLOSE();
    LDA(1, 4);
    GPH_OPEN(); GMFMA(4, 0); GPH_CLOSE();
    GPH_OPEN(); GMFMA(4, 2); GPH_CLOSE();
  }

  #pragma unroll
  for (int mi = 0; mi < 8; mi++) {
    int grow = m0 + wm * 128 + mi * 16 + quad * 4;
    #pragma unroll
    for (int ni = 0; ni < 4; ni++) {
      int gcol = n0 + wn * 64 + ni * 16 + l16;
      float bb = bias[gcol];
      #pragma unroll
      for (int r = 0; r < 4; r++) {
        size_t oi = (size_t)(grow + r) * N + gcol;
        float c = acc[mi][ni][r] + bb;
        outB[oi] = (_Float16)(EPI == 2 ? gelu_act(c) : c);
      }
    }
  }
}

// ---------------- V transpose + bsum accumulation ----------------
// vt[b][h][d][j]; also bsum[b][h*64+d] += b2[h] * sum_j V[b,h,j,d]
__global__ __launch_bounds__(256) void transpose_v(const _Float16* __restrict__ qkv,
                                                   _Float16* __restrict__ vt,
                                                   const float* __restrict__ b2,
                                                   float* __restrict__ bsum) {
  int jt = blockIdx.x;
  int h = blockIdx.y;
  int b = blockIdx.z;
  __shared__ _Float16 tl[64][68];
  int tid = threadIdx.x;
  int j0 = jt * 64;
  #pragma unroll
  for (int k = 0; k < 16; k++) {
    int idx = k * 256 + tid;
    int jr = idx >> 6, dc = idx & 63;
    tl[jr][dc] = qkv[(size_t)(b * N_ + j0 + jr) * (3 * D_) + 2 * D_ + h * 64 + dc];
  }
  __syncthreads();
  #pragma unroll
  for (int k = 0; k < 16; k++) {
    int idx = k * 256 + tid;
    int dr = idx >> 6, jc = idx & 63;
    vt[(size_t)((b * H_ + h) * DH_ + dr) * N_ + j0 + jc] = tl[jc][dr];
  }
  int d = tid & 63, jq = tid >> 6;
  float s = 0.f;
  #pragma unroll
  for (int r = 0; r < 16; r++) s += (float)tl[jq * 16 + r][d];
  atomicAdd(&bsum[b * D_ + h * 64 + d], b2[h] * s);
}

// ---------------- Talking-heads attention (round-6 version, verbatim) -------
// grid (64 i-tiles, 4 b), 1024 thr = 16 waves. Wave index means:
// computeS: head h=wave; mix1: row i=wave; PV: mixed-head e=wave;
// epilogue mix2/store: row i=wave.
__global__ __launch_bounds__(1024, 4) void attn_th(
    const _Float16* __restrict__ qkv, const _Float16* __restrict__ vt,
    const _Float16* __restrict__ w1f, const _Float16* __restrict__ w2f,
    const float* __restrict__ b1f, const float* __restrict__ bsum,
    _Float16* __restrict__ ob) {
  __shared__ __align__(16) _Float16 SP[2 * 16512];  // S planes | P planes
  __shared__ float lsum[272];                       // [e][i] + pad (stride 17)
  _Float16* Sp = SP;
  _Float16* Pp = SP + 16512;

  const int tid = threadIdx.x;
  const int wave = tid >> 6;
  const int lane = tid & 63;
  const int quad = lane >> 4, l16 = lane & 15;
  const int i0 = blockIdx.x * 16;
  const int b = blockIdx.y;
  const size_t bN = (size_t)b * N_;
  const f32x4 zero = {0.f, 0.f, 0.f, 0.f};

  // Q fragments (head=wave), pre-scaled by DH^-1/2 = 0.125 (exact in f16)
  f16x8 qf[2];
  #pragma unroll
  for (int ks = 0; ks < 2; ks++) {
    f16x8 q = *(const f16x8*)(qkv + (bN + i0 + l16) * 3072 + wave * 64 + ks * 32 + quad * 8);
    #pragma unroll
    for (int e = 0; e < 8; e++) q[e] = q[e] * (_Float16)0.125f;
    qf[ks] = q;
  }
  // W1 B-fragment: B[k=h][n=e] = W1[e][h]
  f16x4 w1a = *(const f16x4*)(w1f + l16 * 16 + quad * 4);
  float b1v = b1f[l16];
  f32x4 b1i = {b1v, b1v, b1v, b1v};

  const _Float16* vbase = vt + (size_t)((b * H_ + wave) * DH_ + l16) * N_ + quad * 8;

  f32x4 uacc[4];
  #pragma unroll
  for (int nt = 0; nt < 4; nt++) uacc[nt] = zero;
  float lacc = 0.f;

  // K fragments for the current tile (reloaded in place each iteration)
  f16x8 kcur[4][2];
  auto loadK = [&](int j0) {
    #pragma unroll
    for (int jb = 0; jb < 4; jb++) {
      const _Float16* kb = qkv + (bN + j0 + jb * 16 + l16) * 3072 + 1024 + wave * 64 + quad * 8;
      kcur[jb][0] = *(const f16x8*)kb;
      kcur[jb][1] = *(const f16x8*)(kb + 32);
    }
  };
  loadK(0);

  f16x8 vreg[4];  // first 32-j half of V tile, prefetched

  for (int t = 0; t < 16; t++) {
    int j0 = t * 64;
    // ---- S = (QK^T)^T for head h=wave: C[m=j][n=i] -> S plane [h][i][j]
    f32x4 sres[4];
    #pragma unroll
    for (int jb = 0; jb < 4; jb++) {
      f32x4 s = __builtin_amdgcn_mfma_f32_16x16x32_f16(kcur[jb][0], qf[0], zero, 0, 0, 0);
      sres[jb] = __builtin_amdgcn_mfma_f32_16x16x32_f16(kcur[jb][1], qf[1], s, 0, 0, 0);
    }
    #pragma unroll
    for (int jb = 0; jb < 4; jb++) {
      f16x4 sv;
      #pragma unroll
      for (int r = 0; r < 4; r++) sv[r] = (_Float16)sres[jb][r];
      *(f16x4*)(Sp + lds_off(wave, l16, jb * 16 + quad * 4)) = sv;
    }
    // ---- prefetch next K tile (kcur dead after the MFMAs above) and this
    // tile's first V half; the barrier's vmcnt(0) drain makes them resident.
    if (t < 15) loadK(j0 + 64);
    #pragma unroll
    for (int nt = 0; nt < 4; nt++)
      vreg[nt] = *(const f16x8*)(vbase + (size_t)(nt * 16) * N_ + j0);
    __syncthreads();
    // ---- mix1 (row i=wave) -> exp (unnormalized) -> P planes + l accumulate
    #pragma unroll
    for (int cg = 0; cg < 4; cg++) {
      f16x4 sf;
      #pragma unroll
      for (int t4 = 0; t4 < 4; t4++)
        sf[t4] = Sp[lds_off(quad * 4 + t4, wave, cg * 16 + l16)];
      f32x4 a = __builtin_amdgcn_mfma_f32_16x16x16f16(sf, w1a, b1i, 0, 0, 0);
      f16x4 pv;
      #pragma unroll
      for (int r = 0; r < 4; r++) {
        float e = __expf(a[r]);
        lacc += e;
        pv[r] = (_Float16)e;
      }
      *(f16x4*)(Pp + lds_off(l16, wave, cg * 16 + quad * 4)) = pv;
    }
    __syncthreads();
    // ---- PV: U_e += V @ P_e^T (e=wave): C[m=d][n=i]
    f16x8 pf0 = *(const f16x8*)(Pp + lds_off(wave, l16, quad * 8));
    f16x8 pf1 = *(const f16x8*)(Pp + lds_off(wave, l16, 32 + quad * 8));
    #pragma unroll
    for (int nt = 0; nt < 4; nt++)
      uacc[nt] = __builtin_amdgcn_mfma_f32_16x16x32_f16(vreg[nt], pf0, uacc[nt], 0, 0, 0);
    #pragma unroll
    for (int nt = 0; nt < 4; nt++) {
      f16x8 vf = *(const f16x8*)(vbase + (size_t)(nt * 16) * N_ + j0 + 32);
      uacc[nt] = __builtin_amdgcn_mfma_f32_16x16x32_f16(vf, pf1, uacc[nt], 0, 0, 0);
    }
    // no barrier: next computeS writes S planes (disjoint from P); mix1(t+1)
    // writes P only after the next barrier.
  }

  // ---------------- epilogue ----------------
  lacc += __shfl_xor(lacc, 16);
  lacc += __shfl_xor(lacc, 32);
  __syncthreads();                       // all PV reads of P done
  if (quad == 0) lsum[l16 * 17 + wave] = lacc;
  __syncthreads();
  float invl = 1.0f / lsum[wave * 17 + l16];   // (e=wave, i=l16)

  _Float16* Uf = Sp;
  #pragma unroll
  for (int nt = 0; nt < 4; nt++) {
    f16x4 u;
    #pragma unroll
    for (int r = 0; r < 4; r++) u[r] = (_Float16)(uacc[nt][r] * invl);
    *(f16x4*)(Uf + wave * 1092 + l16 * 68 + nt * 16 + quad * 4) = u;
  }
  __syncthreads();

  f16x4 w2a = *(const f16x4*)(w2f + l16 * 16 + quad * 4);
  #pragma unroll
  for (int cg = 0; cg < 4; cg++) {
    f16x4 af;
    #pragma unroll
    for (int t4 = 0; t4 < 4; t4++)
      af[t4] = Uf[(quad * 4 + t4) * 1092 + wave * 68 + cg * 16 + l16];
    f32x4 o = __builtin_amdgcn_mfma_f32_16x16x16f16(af, w2a, zero, 0, 0, 0);
    f32x4 bs = *(const f32x4*)(bsum + b * D_ + l16 * 64 + cg * 16 + quad * 4);
    f16x4 ov;
    #pragma unroll
    for (int r = 0; r < 4; r++) ov[r] = (_Float16)(o[r] + bs[r]);
    *(f16x4*)(ob + (bN + i0 + wave) * D_ + l16 * 64 + cg * 16 + quad * 4) = ov;
  }
}

// ---------------------------------------------------------------------------
extern "C" void kernel_launch(void* const* d_in, const int* in_sizes, int n_in,
                              void* d_out, int out_size, void* d_ws, size_t ws_size,
                              hipStream_t stream) {
  const float* x      = (const float*)d_in[0];
  const float* ln1_w  = (const float*)d_in[1];
  const float* ln1_b  = (const float*)d_in[2];
  const float* qkv_w  = (const float*)d_in[3];
  const float* qkv_b  = (const float*)d_in[4];
  const float* plw    = (const float*)d_in[5];
  const float* plb    = (const float*)d_in[6];
  const float* pww    = (const float*)d_in[7];
  const float* pwb    = (const float*)d_in[8];
  const float* out_w  = (const float*)d_in[9];
  const float* out_b  = (const float*)d_in[10];
  const float* gamma1 = (const float*)d_in[11];
  const float* ln2_w  = (const float*)d_in[12];
  const float* ln2_b  = (const float*)d_in[13];
  const float* fc1_w  = (const float*)d_in[14];
  const float* fc1_b  = (const float*)d_in[15];
  const float* fc2_w  = (const float*)d_in[16];
  const float* fc2_b  = (const float*)d_in[17];
  const float* gamma2 = (const float*)d_in[18];
  float* out = (float*)d_out;

  char* ws = (char*)d_ws;
  _Float16* wq   = (_Float16*)(ws + 0);          // 6291456 B
  _Float16* wo   = (_Float16*)(ws + 6291456);    // 2097152 B
  _Float16* wf1  = (_Float16*)(ws + 8388608);    // 8388608 B (clean fc1 weights)
  _Float16* wf2  = (_Float16*)(ws + 16777216);   // 8388608 B
  float*    x1   = (float*)   (ws + 25165824);   // 16777216 B (first 17.4 KB host
                                                 //  mix tables/bsum during attn;
                                                 //  overwritten by out-proj after)
  _Float16* ob   = (_Float16*)(ws + 41943040);   // 8388608 B
  _Float16* hb   = (_Float16*)(ws + 50331648);   // 8388608 B
  _Float16* qkvb = (_Float16*)(ws + 58720256);   // 25165824 B
  _Float16* vtb  = (_Float16*)(ws + 83886080);   // 8388608 B
  _Float16* fb   = (_Float16*)(ws + 58720256);   // 33554432 B, aliases qkvb+vtb (dead by then)
  _Float16* w1f  = (_Float16*)(ws + 25165824);          // 512 B
  _Float16* w2f  = (_Float16*)(ws + 25165824 + 512);    // 512 B
  float*    bsum = (float*)   (ws + 25165824 + 1024);   // 16384 B
  if (ws_size < 92274688) return;

  cast_all<<<12289, 256, 0, stream>>>(qkv_w, wq, out_w, wo, fc1_w, wf1, fc2_w, wf2,
                                      plw, pww, w1f, w2f, bsum);

  ln_f16<<<4096, 256, 0, stream>>>(x, ln1_w, ln1_b, hb);
  gemm_nt8<0><<<192, 512, 0, stream>>>(hb, wq, qkv_b, M_, 3 * D_, D_, qkvb);
  transpose_v<<<dim3(16, 16, 4), 256, 0, stream>>>(qkvb, vtb, pwb, bsum);
  attn_th<<<dim3(64, 4), 1024, 0, stream>>>(qkvb, vtb, w1f, w2f, plb, bsum, ob);
  gemm_nt<1, 64, 4><<<dim3(16, 32), 256, 0, stream>>>(ob, wo, out_b, M_, D_, D_, nullptr, x1, x, gamma1);

  ln_f16<<<4096, 256, 0, stream>>>(x1, ln2_w, ln2_b, hb);
  gemm_nt8<2><<<256, 512, 0, stream>>>(hb, wf1, fc1_b, M_, FF_, D_, fb);
  gemm_nt<1, 64, 4><<<dim3(16, 32), 256, 0, stream>>>(fb, wf2, fc2_b, M_, D_, FF_, nullptr, out, x1, gamma2);
}

// Round 7
// 449.013 us; speedup vs baseline: 1.4924x; 1.0020x over previous
//
#include <hip/hip_runtime.h>

// ---------------------------------------------------------------------------
// SelfAttentionLayer (talking-heads) on MI355X gfx950. Round 13.
// r12 consolidation (449.9 us) + three ISOLATED locality changes:
//   * attn_th: decode swap only (b=blockIdx.x, i0=blockIdx.y*16, grid (4,64))
//     -> XCD = b+4*(it&1) serves ONE batch: K+V ws 4 MB = L2-fit. Inner loop
//     VERBATIM r6. Theory: attn moves ~1.07 GB through cache @8.1 TB/s ==
//     L3-BW-bound; decode converts L3 traffic to L2 hits.
//   * out-proj: SWAPXY grid (32,16): XCD owns 4 m-strips (1MB A) + full W
//     (2MB) -> both L2-resident.
//   * fc2: BN=128/OCC=3 (r6-proven config) + SWAPXY grid (32,8): halves
//     A-traffic, 256 blocks = exact fill, 2x ILP for the K=4096 loop.
// ---------------------------------------------------------------------------

typedef _Float16 f16x8 __attribute__((ext_vector_type(8)));
typedef _Float16 f16x4 __attribute__((ext_vector_type(4)));
typedef _Float16 f16x2 __attribute__((ext_vector_type(2)));
typedef float f32x4 __attribute__((ext_vector_type(4)));

#define B_ 4
#define N_ 1024
#define D_ 1024
#define H_ 16
#define DH_ 64
#define FF_ 4096
#define M_ (B_ * N_)

__device__ __forceinline__ float gelu_act(float x) {
  float z = 0.7978845608028654f * (x + 0.044715f * x * x * x);
  return x / (1.0f + __expf(-2.0f * z));
}

__device__ __forceinline__ void ld_lds16(const _Float16* g, _Float16* l) {
  __builtin_amdgcn_global_load_lds((const __attribute__((address_space(1))) void*)g,
                                   (__attribute__((address_space(3))) void*)l, 16, 0, 0);
}

__device__ __forceinline__ int swz8(int i) {
  return (((i >> 2) << 1) ^ (i & 3)) & 7;
}
// S/P plane addressing (v4/v5-proven): plane p stride 1032 f16, row i (64 f16),
// col j chunk-swizzled. mix1 u16 gathers, b64 writes, b128 PV reads <=2-way.
__device__ __forceinline__ int lds_off(int p, int i, int j) {
  int ch = ((j >> 3) ^ swz8(i) ^ ((p >> 2) << 1)) & 7;
  return p * 1032 + i * 64 + (ch << 3) + (j & 7);
}

// ---------------- fused prep: 4 weight casts + mix tables + bsum zero -------
// blocks 0..12287: f32->f16 casts (1024 elts/block). block 12288: tables.
__global__ __launch_bounds__(256) void cast_all(
    const float* __restrict__ a0, _Float16* __restrict__ o0,   // qkv_w  3072*1024
    const float* __restrict__ a1, _Float16* __restrict__ o1,   // out_w  1024*1024
    const float* __restrict__ a2, _Float16* __restrict__ o2,   // fc1_w  4096*1024
    const float* __restrict__ a3, _Float16* __restrict__ o3,   // fc2_w  1024*4096
    const float* __restrict__ W1, const float* __restrict__ W2,
    _Float16* __restrict__ w1f, _Float16* __restrict__ w2f,
    float* __restrict__ bsum) {
  int b = blockIdx.x, t = threadIdx.x;
  const float* in;
  _Float16* out;
  int base;
  if (b < 3072) { in = a0; out = o0; base = b; }
  else if (b < 4096) { in = a1; out = o1; base = b - 3072; }
  else if (b < 8192) { in = a2; out = o2; base = b - 4096; }
  else if (b < 12288) { in = a3; out = o3; base = b - 8192; }
  else {
    w1f[t] = (_Float16)W1[t];
    w2f[t] = (_Float16)W2[t];
    float4 z = {0.f, 0.f, 0.f, 0.f};
    #pragma unroll
    for (int r = 0; r < 4; r++) *(float4*)(bsum + t * 16 + r * 4) = z;
    return;
  }
  int i = (base * 256 + t) * 4;
  float4 v = *(const float4*)(in + i);
  f16x4 o;
  o[0] = (_Float16)v.x; o[1] = (_Float16)v.y; o[2] = (_Float16)v.z; o[3] = (_Float16)v.w;
  *(f16x4*)(out + i) = o;
}

// ---------------- LayerNorm (row of 1024) -> fp16 ----------------
__global__ __launch_bounds__(256) void ln_f16(const float* __restrict__ x,
                                              const float* __restrict__ w,
                                              const float* __restrict__ b,
                                              _Float16* __restrict__ out) {
  int row = blockIdx.x;
  int tid = threadIdx.x;
  const float* xr = x + (size_t)row * D_;
  float4 v = *(const float4*)(xr + tid * 4);
  float s = v.x + v.y + v.z + v.w;
  float sq = v.x * v.x + v.y * v.y + v.z * v.z + v.w * v.w;
  #pragma unroll
  for (int off = 32; off > 0; off >>= 1) {
    s += __shfl_down(s, off);
    sq += __shfl_down(sq, off);
  }
  __shared__ float red[8];
  int wave = tid >> 6, lane = tid & 63;
  if (lane == 0) { red[wave] = s; red[4 + wave] = sq; }
  __syncthreads();
  float ts = red[0] + red[1] + red[2] + red[3];
  float tq = red[4] + red[5] + red[6] + red[7];
  float mean = ts * (1.0f / (float)D_);
  float var = tq * (1.0f / (float)D_) - mean * mean;
  float rs = rsqrtf(var + 1e-5f);
  float4 wv = *(const float4*)(w + tid * 4);
  float4 bv = *(const float4*)(b + tid * 4);
  f16x4 o;
  o[0] = (_Float16)((v.x - mean) * rs * wv.x + bv.x);
  o[1] = (_Float16)((v.y - mean) * rs * wv.y + bv.y);
  o[2] = (_Float16)((v.z - mean) * rs * wv.z + bv.z);
  o[3] = (_Float16)((v.w - mean) * rs * wv.w + bv.w);
  *(f16x4*)(out + (size_t)row * D_ + tid * 4) = o;
}

// ---------------- NT GEMM (128-tile, 2-barrier): for N=1024 shapes ----------------
// SWAPXY=1: blockIdx.x indexes M-tiles (XCD owns m-strips -> A rows L2-local).
template <int EPI, int BN, int OCC, int SWAPXY>
__global__ __launch_bounds__(256, OCC) void gemm_nt(
    const _Float16* __restrict__ A, const _Float16* __restrict__ W,
    const float* __restrict__ bias, int M, int N, int K,
    _Float16* __restrict__ outB, float* __restrict__ outF,
    const float* __restrict__ res, const float* __restrict__ gamma) {
  __shared__ _Float16 As[128 * 64];
  __shared__ _Float16 Bs[BN * 64];
  int tid = threadIdx.x;
  int wave = tid >> 6, lane = tid & 63;
  int quad = lane >> 4, l16 = lane & 15;
  int wm = wave >> 1, wn = wave & 1;
  int m0 = (SWAPXY ? blockIdx.x : blockIdx.y) * 128;
  int n0 = (SWAPXY ? blockIdx.y : blockIdx.x) * BN;
  int lrow = lane >> 3, lcol = (lane & 7) * 8;
  const int NI = (BN == 128) ? 4 : 2;
  const int WN = (BN == 128) ? 64 : 32;

  f32x4 zero = {0.f, 0.f, 0.f, 0.f};
  f32x4 acc[4][NI];
  #pragma unroll
  for (int i = 0; i < 4; i++)
    #pragma unroll
    for (int j = 0; j < NI; j++) acc[i][j] = zero;

  for (int k0 = 0; k0 < K; k0 += 64) {
    __syncthreads();
    #pragma unroll
    for (int c = 0; c < 4; c++) {
      int rb = c * 32 + wave * 8;
      ld_lds16(A + (size_t)(m0 + rb + lrow) * K + k0 + lcol, As + rb * 64);
      if (BN == 128 || c < 2)
        ld_lds16(W + (size_t)(n0 + rb + lrow) * K + k0 + lcol, Bs + rb * 64);
    }
    __syncthreads();
    #pragma unroll
    for (int ks = 0; ks < 2; ks++) {
      int kk = ks * 32 + quad * 8;
      f16x8 a[4], bfr[NI];
      #pragma unroll
      for (int i = 0; i < 4; i++) a[i] = *(const f16x8*)(As + (wm * 64 + i * 16 + l16) * 64 + kk);
      #pragma unroll
      for (int i = 0; i < NI; i++) bfr[i] = *(const f16x8*)(Bs + (wn * WN + i * 16 + l16) * 64 + kk);
      #pragma unroll
      for (int mi = 0; mi < 4; mi++)
        #pragma unroll
        for (int ni = 0; ni < NI; ni++)
          acc[mi][ni] = __builtin_amdgcn_mfma_f32_16x16x32_f16(a[mi], bfr[ni], acc[mi][ni], 0, 0, 0);
    }
  }

  #pragma unroll
  for (int mi = 0; mi < 4; mi++) {
    int grow_base = m0 + wm * 64 + mi * 16 + quad * 4;
    #pragma unroll
    for (int ni = 0; ni < NI; ni++) {
      int gcol = n0 + wn * WN + ni * 16 + l16;
      float bb = bias[gcol];
      float gm = (EPI == 1) ? gamma[gcol] : 0.f;
      #pragma unroll
      for (int r = 0; r < 4; r++) {
        size_t oi = (size_t)(grow_base + r) * N + gcol;
        float c = acc[mi][ni][r] + bb;
        if (EPI == 0) {
          outB[oi] = (_Float16)c;
        } else if (EPI == 1) {
          outF[oi] = res[oi] + gm * c;
        } else {
          outB[oi] = (_Float16)gelu_act(c);
        }
      }
    }
  }
}

// ---------------- 8-phase 256x256 NT GEMM (K=1024, M,N % 256 == 0) ----------------
#define GPH_OPEN()                                      \
  __builtin_amdgcn_sched_barrier(0);                    \
  __builtin_amdgcn_s_barrier();                         \
  asm volatile("s_waitcnt lgkmcnt(0)" ::: "memory");    \
  __builtin_amdgcn_sched_barrier(0);                    \
  __builtin_amdgcn_s_setprio(1)

#define GPH_CLOSE()                                     \
  __builtin_amdgcn_s_setprio(0);                        \
  __builtin_amdgcn_sched_barrier(0);                    \
  __builtin_amdgcn_s_barrier()

#define GPH_CLOSE_VM(n)                                 \
  __builtin_amdgcn_s_setprio(0);                        \
  __builtin_amdgcn_sched_barrier(0);                    \
  asm volatile("s_waitcnt vmcnt(" #n ")" ::: "memory"); \
  __builtin_amdgcn_s_barrier()

#define GMFMA(MB, NB)                                                         \
  _Pragma("unroll") for (int ks = 0; ks < 2; ks++)                            \
  _Pragma("unroll") for (int mi = 0; mi < 4; mi++)                            \
  _Pragma("unroll") for (int ni = 0; ni < 2; ni++)                            \
    acc[MB + mi][NB + ni] = __builtin_amdgcn_mfma_f32_16x16x32_f16(           \
        ar[mi][ks], br[NB + ni][ks], acc[MB + mi][NB + ni], 0, 0, 0)

#define LDA(buf, MB)                                            \
  _Pragma("unroll") for (int ks = 0; ks < 2; ks++)              \
  _Pragma("unroll") for (int mi = 0; mi < 4; mi++)              \
    ar[mi][ks] = rdf(&lds[buf][0][wm][0], MB + mi, ks)

#define LDB(buf, NB)                                            \
  _Pragma("unroll") for (int ks = 0; ks < 2; ks++)              \
  _Pragma("unroll") for (int ni = 0; ni < 2; ni++)              \
    br[NB + ni][ks] = rdf(&lds[buf][1][wn >> 1][0], fbB + NB + ni, ks)

template <int EPI>
__global__ __launch_bounds__(512, 2) void gemm_nt8(
    const _Float16* __restrict__ A, const _Float16* __restrict__ W,
    const float* __restrict__ bias, int M, int N, int K,
    _Float16* __restrict__ outB) {
  __shared__ _Float16 lds[2][2][2][8192];  // [buf][A=0/B=1][row-half][128*64]
  const int tid = threadIdx.x;
  const int wv = tid >> 6, lane = tid & 63;
  const int quad = lane >> 4, l16 = lane & 15;
  const int wm = wv >> 2, wn = wv & 3;
  const int fbB = (wn & 1) * 4;
  const int wg = ((int)blockIdx.x & 7) * ((int)gridDim.x >> 3) + ((int)blockIdx.x >> 3);
  const int m0 = (wg & 15) << 8;   // M/256 == 16 for all uses here
  const int n0 = (wg >> 4) << 8;
  const int gc = ((lane & 7) ^ (lane >> 3)) << 3;
  const int srow = wv * 8 + (lane >> 3);

  auto stageA = [&](int kt, int h) {
    const _Float16* g = A + (size_t)(m0 + h * 128 + srow) * K + kt * 64 + gc;
    _Float16* l = &lds[kt & 1][0][h][wv * 512];
    ld_lds16(g, l);
    ld_lds16(g + (size_t)64 * K, l + 4096);
  };
  auto stageB = [&](int kt, int h) {
    const _Float16* g = W + (size_t)(n0 + h * 128 + srow) * K + kt * 64 + gc;
    _Float16* l = &lds[kt & 1][1][h][wv * 512];
    ld_lds16(g, l);
    ld_lds16(g + (size_t)64 * K, l + 4096);
  };
  auto rdf = [&](const _Float16* base, int fi, int ks) -> f16x8 {
    int row = fi * 16 + l16;
    int pc = ((ks << 2) + quad) ^ (l16 & 7);
    return *(const f16x8*)(base + row * 64 + (pc << 3));
  };

  f32x4 acc[8][4];
  const f32x4 zero = {0.f, 0.f, 0.f, 0.f};
  #pragma unroll
  for (int i = 0; i < 8; i++)
    #pragma unroll
    for (int j = 0; j < 4; j++) acc[i][j] = zero;
  f16x8 ar[4][2], br[4][2];

  stageA(0, 0); stageA(0, 1); stageB(0, 0); stageB(0, 1);
  stageB(1, 0); stageB(1, 1);
  asm volatile("s_waitcnt vmcnt(4)" ::: "memory");
  __builtin_amdgcn_s_barrier();

  const int NT = K >> 6;        // 16
  const int ITERS = NT >> 1;    // 8
  for (int it = 0; it < ITERS - 1; ++it) {
    const int t0 = it * 2;
    LDA(0, 0); LDB(0, 0); stageA(t0 + 1, 0);
    GPH_OPEN(); GMFMA(0, 0); GPH_CLOSE();
    LDB(0, 2); stageA(t0 + 1, 1);
    GPH_OPEN(); GMFMA(0, 2); GPH_CLOSE();
    LDA(0, 4); stageB(t0 + 2, 0);
    GPH_OPEN(); GMFMA(4, 0); GPH_CLOSE();
    stageB(t0 + 2, 1);
    GPH_OPEN(); GMFMA(4, 2); GPH_CLOSE_VM(4);
    LDA(1, 0); LDB(1, 0); stageA(t0 + 2, 0);
    GPH_OPEN(); GMFMA(0, 0); GPH_CLOSE();
    LDB(1, 2); stageA(t0 + 2, 1);
    GPH_OPEN(); GMFMA(0, 2); GPH_CLOSE();
    LDA(1, 4); stageB(t0 + 3, 0);
    GPH_OPEN(); GMFMA(4, 0); GPH_CLOSE();
    stageB(t0 + 3, 1);
    GPH_OPEN(); GMFMA(4, 2); GPH_CLOSE_VM(4);
  }
  {
    LDA(0, 0); LDB(0, 0); stageA(NT - 1, 0);
    GPH_OPEN(); GMFMA(0, 0); GPH_CLOSE();
    LDB(0, 2); stageA(NT - 1, 1);
    GPH_OPEN(); GMFMA(0, 2); GPH_CLOSE();
    LDA(0, 4);
    GPH_OPEN(); GMFMA(4, 0); GPH_CLOSE();
    GPH_OPEN(); GMFMA(4, 2); GPH_CLOSE_VM(0);
    LDA(1, 0); LDB(1, 0);
    GPH_OPEN(); GMFMA(0, 0); GPH_CLOSE();
    LDB(1, 2);
    GPH_OPEN(); GMFMA(0, 2); GPH_CLOSE();
    LDA(1, 4);
    GPH_OPEN(); GMFMA(4, 0); GPH_CLOSE();
    GPH_OPEN(); GMFMA(4, 2); GPH_CLOSE();
  }

  #pragma unroll
  for (int mi = 0; mi < 8; mi++) {
    int grow = m0 + wm * 128 + mi * 16 + quad * 4;
    #pragma unroll
    for (int ni = 0; ni < 4; ni++) {
      int gcol = n0 + wn * 64 + ni * 16 + l16;
      float bb = bias[gcol];
      #pragma unroll
      for (int r = 0; r < 4; r++) {
        size_t oi = (size_t)(grow + r) * N + gcol;
        float c = acc[mi][ni][r] + bb;
        outB[oi] = (_Float16)(EPI == 2 ? gelu_act(c) : c);
      }
    }
  }
}

// ---------------- V transpose + bsum accumulation ----------------
// vt[b][h][d][j]; also bsum[b][h*64+d] += b2[h] * sum_j V[b,h,j,d]
__global__ __launch_bounds__(256) void transpose_v(const _Float16* __restrict__ qkv,
                                                   _Float16* __restrict__ vt,
                                                   const float* __restrict__ b2,
                                                   float* __restrict__ bsum) {
  int jt = blockIdx.x;
  int h = blockIdx.y;
  int b = blockIdx.z;
  __shared__ _Float16 tl[64][68];
  int tid = threadIdx.x;
  int j0 = jt * 64;
  #pragma unroll
  for (int k = 0; k < 16; k++) {
    int idx = k * 256 + tid;
    int jr = idx >> 6, dc = idx & 63;
    tl[jr][dc] = qkv[(size_t)(b * N_ + j0 + jr) * (3 * D_) + 2 * D_ + h * 64 + dc];
  }
  __syncthreads();
  #pragma unroll
  for (int k = 0; k < 16; k++) {
    int idx = k * 256 + tid;
    int dr = idx >> 6, jc = idx & 63;
    vt[(size_t)((b * H_ + h) * DH_ + dr) * N_ + j0 + jc] = tl[jc][dr];
  }
  int d = tid & 63, jq = tid >> 6;
  float s = 0.f;
  #pragma unroll
  for (int r = 0; r < 16; r++) s += (float)tl[jq * 16 + r][d];
  atomicAdd(&bsum[b * D_ + h * 64 + d], b2[h] * s);
}

// ---------------- Talking-heads attention (r6 loop; XCD-local decode) -------
// grid (4 b, 64 i-tiles): linear id = b + 4*it -> XCD = b + 4*(it&1), so each
// XCD serves ONE batch: K+V working set 4 MB = L2-fit. Inner loop = r6.
__global__ __launch_bounds__(1024, 4) void attn_th(
    const _Float16* __restrict__ qkv, const _Float16* __restrict__ vt,
    const _Float16* __restrict__ w1f, const _Float16* __restrict__ w2f,
    const float* __restrict__ b1f, const float* __restrict__ bsum,
    _Float16* __restrict__ ob) {
  __shared__ __align__(16) _Float16 SP[2 * 16512];  // S planes | P planes
  __shared__ float lsum[272];                       // [e][i] + pad (stride 17)
  _Float16* Sp = SP;
  _Float16* Pp = SP + 16512;

  const int tid = threadIdx.x;
  const int wave = tid >> 6;
  const int lane = tid & 63;
  const int quad = lane >> 4, l16 = lane & 15;
  const int i0 = blockIdx.y * 16;   // decode swap (was blockIdx.x)
  const int b = blockIdx.x;         // decode swap (was blockIdx.y)
  const size_t bN = (size_t)b * N_;
  const f32x4 zero = {0.f, 0.f, 0.f, 0.f};

  // Q fragments (head=wave), pre-scaled by DH^-1/2 = 0.125 (exact in f16)
  f16x8 qf[2];
  #pragma unroll
  for (int ks = 0; ks < 2; ks++) {
    f16x8 q = *(const f16x8*)(qkv + (bN + i0 + l16) * 3072 + wave * 64 + ks * 32 + quad * 8);
    #pragma unroll
    for (int e = 0; e < 8; e++) q[e] = q[e] * (_Float16)0.125f;
    qf[ks] = q;
  }
  // W1 B-fragment: B[k=h][n=e] = W1[e][h]
  f16x4 w1a = *(const f16x4*)(w1f + l16 * 16 + quad * 4);
  float b1v = b1f[l16];
  f32x4 b1i = {b1v, b1v, b1v, b1v};

  const _Float16* vbase = vt + (size_t)((b * H_ + wave) * DH_ + l16) * N_ + quad * 8;

  f32x4 uacc[4];
  #pragma unroll
  for (int nt = 0; nt < 4; nt++) uacc[nt] = zero;
  float lacc = 0.f;

  // K fragments for the current tile (reloaded in place each iteration)
  f16x8 kcur[4][2];
  auto loadK = [&](int j0) {
    #pragma unroll
    for (int jb = 0; jb < 4; jb++) {
      const _Float16* kb = qkv + (bN + j0 + jb * 16 + l16) * 3072 + 1024 + wave * 64 + quad * 8;
      kcur[jb][0] = *(const f16x8*)kb;
      kcur[jb][1] = *(const f16x8*)(kb + 32);
    }
  };
  loadK(0);

  f16x8 vreg[4];  // first 32-j half of V tile, prefetched

  for (int t = 0; t < 16; t++) {
    int j0 = t * 64;
    // ---- S = (QK^T)^T for head h=wave: C[m=j][n=i] -> S plane [h][i][j]
    f32x4 sres[4];
    #pragma unroll
    for (int jb = 0; jb < 4; jb++) {
      f32x4 s = __builtin_amdgcn_mfma_f32_16x16x32_f16(kcur[jb][0], qf[0], zero, 0, 0, 0);
      sres[jb] = __builtin_amdgcn_mfma_f32_16x16x32_f16(kcur[jb][1], qf[1], s, 0, 0, 0);
    }
    #pragma unroll
    for (int jb = 0; jb < 4; jb++) {
      f16x4 sv;
      #pragma unroll
      for (int r = 0; r < 4; r++) sv[r] = (_Float16)sres[jb][r];
      *(f16x4*)(Sp + lds_off(wave, l16, jb * 16 + quad * 4)) = sv;
    }
    // ---- prefetch next K tile (kcur dead after the MFMAs above) and this
    // tile's first V half; the barrier's vmcnt(0) drain makes them resident.
    if (t < 15) loadK(j0 + 64);
    #pragma unroll
    for (int nt = 0; nt < 4; nt++)
      vreg[nt] = *(const f16x8*)(vbase + (size_t)(nt * 16) * N_ + j0);
    __syncthreads();
    // ---- mix1 (row i=wave) -> exp (unnormalized) -> P planes + l accumulate
    #pragma unroll
    for (int cg = 0; cg < 4; cg++) {
      f16x4 sf;
      #pragma unroll
      for (int t4 = 0; t4 < 4; t4++)
        sf[t4] = Sp[lds_off(quad * 4 + t4, wave, cg * 16 + l16)];
      f32x4 a = __builtin_amdgcn_mfma_f32_16x16x16f16(sf, w1a, b1i, 0, 0, 0);
      f16x4 pv;
      #pragma unroll
      for (int r = 0; r < 4; r++) {
        float e = __expf(a[r]);
        lacc += e;
        pv[r] = (_Float16)e;
      }
      *(f16x4*)(Pp + lds_off(l16, wave, cg * 16 + quad * 4)) = pv;
    }
    __syncthreads();
    // ---- PV: U_e += V @ P_e^T (e=wave): C[m=d][n=i]
    f16x8 pf0 = *(const f16x8*)(Pp + lds_off(wave, l16, quad * 8));
    f16x8 pf1 = *(const f16x8*)(Pp + lds_off(wave, l16, 32 + quad * 8));
    #pragma unroll
    for (int nt = 0; nt < 4; nt++)
      uacc[nt] = __builtin_amdgcn_mfma_f32_16x16x32_f16(vreg[nt], pf0, uacc[nt], 0, 0, 0);
    #pragma unroll
    for (int nt = 0; nt < 4; nt++) {
      f16x8 vf = *(const f16x8*)(vbase + (size_t)(nt * 16) * N_ + j0 + 32);
      uacc[nt] = __builtin_amdgcn_mfma_f32_16x16x32_f16(vf, pf1, uacc[nt], 0, 0, 0);
    }
    // no barrier: next computeS writes S planes (disjoint from P); mix1(t+1)
    // writes P only after the next barrier.
  }

  // ---------------- epilogue ----------------
  lacc += __shfl_xor(lacc, 16);
  lacc += __shfl_xor(lacc, 32);
  __syncthreads();                       // all PV reads of P done
  if (quad == 0) lsum[l16 * 17 + wave] = lacc;
  __syncthreads();
  float invl = 1.0f / lsum[wave * 17 + l16];   // (e=wave, i=l16)

  _Float16* Uf = Sp;
  #pragma unroll
  for (int nt = 0; nt < 4; nt++) {
    f16x4 u;
    #pragma unroll
    for (int r = 0; r < 4; r++) u[r] = (_Float16)(uacc[nt][r] * invl);
    *(f16x4*)(Uf + wave * 1092 + l16 * 68 + nt * 16 + quad * 4) = u;
  }
  __syncthreads();

  f16x4 w2a = *(const f16x4*)(w2f + l16 * 16 + quad * 4);
  #pragma unroll
  for (int cg = 0; cg < 4; cg++) {
    f16x4 af;
    #pragma unroll
    for (int t4 = 0; t4 < 4; t4++)
      af[t4] = Uf[(quad * 4 + t4) * 1092 + wave * 68 + cg * 16 + l16];
    f32x4 o = __builtin_amdgcn_mfma_f32_16x16x16f16(af, w2a, zero, 0, 0, 0);
    f32x4 bs = *(const f32x4*)(bsum + b * D_ + l16 * 64 + cg * 16 + quad * 4);
    f16x4 ov;
    #pragma unroll
    for (int r = 0; r < 4; r++) ov[r] = (_Float16)(o[r] + bs[r]);
    *(f16x4*)(ob + (bN + i0 + wave) * D_ + l16 * 64 + cg * 16 + quad * 4) = ov;
  }
}

// ---------------------------------------------------------------------------
extern "C" void kernel_launch(void* const* d_in, const int* in_sizes, int n_in,
                              void* d_out, int out_size, void* d_ws, size_t ws_size,
                              hipStream_t stream) {
  const float* x      = (const float*)d_in[0];
  const float* ln1_w  = (const float*)d_in[1];
  const float* ln1_b  = (const float*)d_in[2];
  const float* qkv_w  = (const float*)d_in[3];
  const float* qkv_b  = (const float*)d_in[4];
  const float* plw    = (const float*)d_in[5];
  const float* plb    = (const float*)d_in[6];
  const float* pww    = (const float*)d_in[7];
  const float* pwb    = (const float*)d_in[8];
  const float* out_w  = (const float*)d_in[9];
  const float* out_b  = (const float*)d_in[10];
  const float* gamma1 = (const float*)d_in[11];
  const float* ln2_w  = (const float*)d_in[12];
  const float* ln2_b  = (const float*)d_in[13];
  const float* fc1_w  = (const float*)d_in[14];
  const float* fc1_b  = (const float*)d_in[15];
  const float* fc2_w  = (const float*)d_in[16];
  const float* fc2_b  = (const float*)d_in[17];
  const float* gamma2 = (const float*)d_in[18];
  float* out = (float*)d_out;

  char* ws = (char*)d_ws;
  _Float16* wq   = (_Float16*)(ws + 0);          // 6291456 B
  _Float16* wo   = (_Float16*)(ws + 6291456);    // 2097152 B
  _Float16* wf1  = (_Float16*)(ws + 8388608);    // 8388608 B (clean fc1 weights)
  _Float16* wf2  = (_Float16*)(ws + 16777216);   // 8388608 B
  float*    x1   = (float*)   (ws + 25165824);   // 16777216 B (first 17.4 KB host
                                                 //  mix tables/bsum during attn;
                                                 //  overwritten by out-proj after)
  _Float16* ob   = (_Float16*)(ws + 41943040);   // 8388608 B
  _Float16* hb   = (_Float16*)(ws + 50331648);   // 8388608 B
  _Float16* qkvb = (_Float16*)(ws + 58720256);   // 25165824 B
  _Float16* vtb  = (_Float16*)(ws + 83886080);   // 8388608 B
  _Float16* fb   = (_Float16*)(ws + 58720256);   // 33554432 B, aliases qkvb+vtb (dead by then)
  _Float16* w1f  = (_Float16*)(ws + 25165824);          // 512 B
  _Float16* w2f  = (_Float16*)(ws + 25165824 + 512);    // 512 B
  float*    bsum = (float*)   (ws + 25165824 + 1024);   // 16384 B
  if (ws_size < 92274688) return;

  cast_all<<<12289, 256, 0, stream>>>(qkv_w, wq, out_w, wo, fc1_w, wf1, fc2_w, wf2,
                                      plw, pww, w1f, w2f, bsum);

  ln_f16<<<4096, 256, 0, stream>>>(x, ln1_w, ln1_b, hb);
  gemm_nt8<0><<<192, 512, 0, stream>>>(hb, wq, qkv_b, M_, 3 * D_, D_, qkvb);
  transpose_v<<<dim3(16, 16, 4), 256, 0, stream>>>(qkvb, vtb, pwb, bsum);
  attn_th<<<dim3(4, 64), 1024, 0, stream>>>(qkvb, vtb, w1f, w2f, plb, bsum, ob);
  gemm_nt<1, 64, 4, 1><<<dim3(32, 16), 256, 0, stream>>>(ob, wo, out_b, M_, D_, D_, nullptr, x1, x, gamma1);

  ln_f16<<<4096, 256, 0, stream>>>(x1, ln2_w, ln2_b, hb);
  gemm_nt8<2><<<256, 512, 0, stream>>>(hb, wf1, fc1_b, M_, FF_, D_, fb);
  gemm_nt<1, 128, 3, 1><<<dim3(32, 8), 256, 0, stream>>>(fb, wf2, fc2_b, M_, D_, FF_, nullptr, out, x1, gamma2);
}

// Round 8
// 426.952 us; speedup vs baseline: 1.5695x; 1.0517x over previous
//
#include <hip/hip_runtime.h>

// ---------------------------------------------------------------------------
// SelfAttentionLayer (talking-heads) on MI355X gfx950. Round 14.
// r13 (449.0 us) + fc2 split-K:
//   * fc2 (M=4096,N=1024,K=4096) moves to the PROVEN 8-phase gemm_nt8 loop
//     via 4-way K-split: each split runs the identical K=1024 16-tile
//     schedule (kt0 offset only). Grid 64 tile-positions x 4 splits = 256
//     blocks = exact fill. f16 partials -> two dead 16.8MB ws regions;
//     fc2_combine applies (sum + bias)*gamma2 + x1 in f32.
//   * attn arc CLOSED at 133 us: r13 proved FETCH 76->27MB with dur flat ->
//     structure-latency-bound, not BW/occupancy/locality. Do not touch.
//   * everything else = r13 (attn XCD decode, SWAPXY out-proj, 8-phase
//     qkv/fc1, fused prep).
// ---------------------------------------------------------------------------

typedef _Float16 f16x8 __attribute__((ext_vector_type(8)));
typedef _Float16 f16x4 __attribute__((ext_vector_type(4)));
typedef _Float16 f16x2 __attribute__((ext_vector_type(2)));
typedef float f32x4 __attribute__((ext_vector_type(4)));

#define B_ 4
#define N_ 1024
#define D_ 1024
#define H_ 16
#define DH_ 64
#define FF_ 4096
#define M_ (B_ * N_)

__device__ __forceinline__ float gelu_act(float x) {
  float z = 0.7978845608028654f * (x + 0.044715f * x * x * x);
  return x / (1.0f + __expf(-2.0f * z));
}

__device__ __forceinline__ void ld_lds16(const _Float16* g, _Float16* l) {
  __builtin_amdgcn_global_load_lds((const __attribute__((address_space(1))) void*)g,
                                   (__attribute__((address_space(3))) void*)l, 16, 0, 0);
}

__device__ __forceinline__ int swz8(int i) {
  return (((i >> 2) << 1) ^ (i & 3)) & 7;
}
// S/P plane addressing (v4/v5-proven): plane p stride 1032 f16, row i (64 f16),
// col j chunk-swizzled. mix1 u16 gathers, b64 writes, b128 PV reads <=2-way.
__device__ __forceinline__ int lds_off(int p, int i, int j) {
  int ch = ((j >> 3) ^ swz8(i) ^ ((p >> 2) << 1)) & 7;
  return p * 1032 + i * 64 + (ch << 3) + (j & 7);
}

// ---------------- fused prep: 4 weight casts + mix tables + bsum zero -------
// blocks 0..12287: f32->f16 casts (1024 elts/block). block 12288: tables.
__global__ __launch_bounds__(256) void cast_all(
    const float* __restrict__ a0, _Float16* __restrict__ o0,   // qkv_w  3072*1024
    const float* __restrict__ a1, _Float16* __restrict__ o1,   // out_w  1024*1024
    const float* __restrict__ a2, _Float16* __restrict__ o2,   // fc1_w  4096*1024
    const float* __restrict__ a3, _Float16* __restrict__ o3,   // fc2_w  1024*4096
    const float* __restrict__ W1, const float* __restrict__ W2,
    _Float16* __restrict__ w1f, _Float16* __restrict__ w2f,
    float* __restrict__ bsum) {
  int b = blockIdx.x, t = threadIdx.x;
  const float* in;
  _Float16* out;
  int base;
  if (b < 3072) { in = a0; out = o0; base = b; }
  else if (b < 4096) { in = a1; out = o1; base = b - 3072; }
  else if (b < 8192) { in = a2; out = o2; base = b - 4096; }
  else if (b < 12288) { in = a3; out = o3; base = b - 8192; }
  else {
    w1f[t] = (_Float16)W1[t];
    w2f[t] = (_Float16)W2[t];
    float4 z = {0.f, 0.f, 0.f, 0.f};
    #pragma unroll
    for (int r = 0; r < 4; r++) *(float4*)(bsum + t * 16 + r * 4) = z;
    return;
  }
  int i = (base * 256 + t) * 4;
  float4 v = *(const float4*)(in + i);
  f16x4 o;
  o[0] = (_Float16)v.x; o[1] = (_Float16)v.y; o[2] = (_Float16)v.z; o[3] = (_Float16)v.w;
  *(f16x4*)(out + i) = o;
}

// ---------------- LayerNorm (row of 1024) -> fp16 ----------------
__global__ __launch_bounds__(256) void ln_f16(const float* __restrict__ x,
                                              const float* __restrict__ w,
                                              const float* __restrict__ b,
                                              _Float16* __restrict__ out) {
  int row = blockIdx.x;
  int tid = threadIdx.x;
  const float* xr = x + (size_t)row * D_;
  float4 v = *(const float4*)(xr + tid * 4);
  float s = v.x + v.y + v.z + v.w;
  float sq = v.x * v.x + v.y * v.y + v.z * v.z + v.w * v.w;
  #pragma unroll
  for (int off = 32; off > 0; off >>= 1) {
    s += __shfl_down(s, off);
    sq += __shfl_down(sq, off);
  }
  __shared__ float red[8];
  int wave = tid >> 6, lane = tid & 63;
  if (lane == 0) { red[wave] = s; red[4 + wave] = sq; }
  __syncthreads();
  float ts = red[0] + red[1] + red[2] + red[3];
  float tq = red[4] + red[5] + red[6] + red[7];
  float mean = ts * (1.0f / (float)D_);
  float var = tq * (1.0f / (float)D_) - mean * mean;
  float rs = rsqrtf(var + 1e-5f);
  float4 wv = *(const float4*)(w + tid * 4);
  float4 bv = *(const float4*)(b + tid * 4);
  f16x4 o;
  o[0] = (_Float16)((v.x - mean) * rs * wv.x + bv.x);
  o[1] = (_Float16)((v.y - mean) * rs * wv.y + bv.y);
  o[2] = (_Float16)((v.z - mean) * rs * wv.z + bv.z);
  o[3] = (_Float16)((v.w - mean) * rs * wv.w + bv.w);
  *(f16x4*)(out + (size_t)row * D_ + tid * 4) = o;
}

// ---------------- NT GEMM (128-tile, 2-barrier): out-proj ----------------
// SWAPXY=1: blockIdx.x indexes M-tiles (XCD owns m-strips -> A rows L2-local).
template <int EPI, int BN, int OCC, int SWAPXY>
__global__ __launch_bounds__(256, OCC) void gemm_nt(
    const _Float16* __restrict__ A, const _Float16* __restrict__ W,
    const float* __restrict__ bias, int M, int N, int K,
    _Float16* __restrict__ outB, float* __restrict__ outF,
    const float* __restrict__ res, const float* __restrict__ gamma) {
  __shared__ _Float16 As[128 * 64];
  __shared__ _Float16 Bs[BN * 64];
  int tid = threadIdx.x;
  int wave = tid >> 6, lane = tid & 63;
  int quad = lane >> 4, l16 = lane & 15;
  int wm = wave >> 1, wn = wave & 1;
  int m0 = (SWAPXY ? blockIdx.x : blockIdx.y) * 128;
  int n0 = (SWAPXY ? blockIdx.y : blockIdx.x) * BN;
  int lrow = lane >> 3, lcol = (lane & 7) * 8;
  const int NI = (BN == 128) ? 4 : 2;
  const int WN = (BN == 128) ? 64 : 32;

  f32x4 zero = {0.f, 0.f, 0.f, 0.f};
  f32x4 acc[4][NI];
  #pragma unroll
  for (int i = 0; i < 4; i++)
    #pragma unroll
    for (int j = 0; j < NI; j++) acc[i][j] = zero;

  for (int k0 = 0; k0 < K; k0 += 64) {
    __syncthreads();
    #pragma unroll
    for (int c = 0; c < 4; c++) {
      int rb = c * 32 + wave * 8;
      ld_lds16(A + (size_t)(m0 + rb + lrow) * K + k0 + lcol, As + rb * 64);
      if (BN == 128 || c < 2)
        ld_lds16(W + (size_t)(n0 + rb + lrow) * K + k0 + lcol, Bs + rb * 64);
    }
    __syncthreads();
    #pragma unroll
    for (int ks = 0; ks < 2; ks++) {
      int kk = ks * 32 + quad * 8;
      f16x8 a[4], bfr[NI];
      #pragma unroll
      for (int i = 0; i < 4; i++) a[i] = *(const f16x8*)(As + (wm * 64 + i * 16 + l16) * 64 + kk);
      #pragma unroll
      for (int i = 0; i < NI; i++) bfr[i] = *(const f16x8*)(Bs + (wn * WN + i * 16 + l16) * 64 + kk);
      #pragma unroll
      for (int mi = 0; mi < 4; mi++)
        #pragma unroll
        for (int ni = 0; ni < NI; ni++)
          acc[mi][ni] = __builtin_amdgcn_mfma_f32_16x16x32_f16(a[mi], bfr[ni], acc[mi][ni], 0, 0, 0);
    }
  }

  #pragma unroll
  for (int mi = 0; mi < 4; mi++) {
    int grow_base = m0 + wm * 64 + mi * 16 + quad * 4;
    #pragma unroll
    for (int ni = 0; ni < NI; ni++) {
      int gcol = n0 + wn * WN + ni * 16 + l16;
      float bb = bias[gcol];
      float gm = (EPI == 1) ? gamma[gcol] : 0.f;
      #pragma unroll
      for (int r = 0; r < 4; r++) {
        size_t oi = (size_t)(grow_base + r) * N + gcol;
        float c = acc[mi][ni][r] + bb;
        if (EPI == 0) {
          outB[oi] = (_Float16)c;
        } else if (EPI == 1) {
          outF[oi] = res[oi] + gm * c;
        } else {
          outB[oi] = (_Float16)gelu_act(c);
        }
      }
    }
  }
}

// ---------------- 8-phase 256x256 NT GEMM ----------------
// EPI 0: plain f16 out (qkv). EPI 2: gelu f16 out (fc1). Both: K=1024 full.
// EPI 3: split-K partial (fc2): grid = 64 tile-positions x 4 splits; each
// split runs the identical 16-tile K=1024 schedule at kt offset split*16 and
// writes f16 partials (no bias) to (split<2?outB:outB2)+(split&1)*M*N.
#define GPH_OPEN()                                      \
  __builtin_amdgcn_sched_barrier(0);                    \
  __builtin_amdgcn_s_barrier();                         \
  asm volatile("s_waitcnt lgkmcnt(0)" ::: "memory");    \
  __builtin_amdgcn_sched_barrier(0);                    \
  __builtin_amdgcn_s_setprio(1)

#define GPH_CLOSE()                                     \
  __builtin_amdgcn_s_setprio(0);                        \
  __builtin_amdgcn_sched_barrier(0);                    \
  __builtin_amdgcn_s_barrier()

#define GPH_CLOSE_VM(n)                                 \
  __builtin_amdgcn_s_setprio(0);                        \
  __builtin_amdgcn_sched_barrier(0);                    \
  asm volatile("s_waitcnt vmcnt(" #n ")" ::: "memory"); \
  __builtin_amdgcn_s_barrier()

#define GMFMA(MB, NB)                                                         \
  _Pragma("unroll") for (int ks = 0; ks < 2; ks++)                            \
  _Pragma("unroll") for (int mi = 0; mi < 4; mi++)                            \
  _Pragma("unroll") for (int ni = 0; ni < 2; ni++)                            \
    acc[MB + mi][NB + ni] = __builtin_amdgcn_mfma_f32_16x16x32_f16(           \
        ar[mi][ks], br[NB + ni][ks], acc[MB + mi][NB + ni], 0, 0, 0)

#define LDA(buf, MB)                                            \
  _Pragma("unroll") for (int ks = 0; ks < 2; ks++)              \
  _Pragma("unroll") for (int mi = 0; mi < 4; mi++)              \
    ar[mi][ks] = rdf(&lds[buf][0][wm][0], MB + mi, ks)

#define LDB(buf, NB)                                            \
  _Pragma("unroll") for (int ks = 0; ks < 2; ks++)              \
  _Pragma("unroll") for (int ni = 0; ni < 2; ni++)              \
    br[NB + ni][ks] = rdf(&lds[buf][1][wn >> 1][0], fbB + NB + ni, ks)

template <int EPI>
__global__ __launch_bounds__(512, 2) void gemm_nt8(
    const _Float16* __restrict__ A, const _Float16* __restrict__ W,
    const float* __restrict__ bias, int M, int N, int K,
    _Float16* __restrict__ outB, _Float16* __restrict__ outB2) {
  __shared__ _Float16 lds[2][2][2][8192];  // [buf][A=0/B=1][row-half][128*64]
  const int tid = threadIdx.x;
  const int wv = tid >> 6, lane = tid & 63;
  const int quad = lane >> 4, l16 = lane & 15;
  const int wm = wv >> 2, wn = wv & 3;
  const int fbB = (wn & 1) * 4;
  const int wg = ((int)blockIdx.x & 7) * ((int)gridDim.x >> 3) + ((int)blockIdx.x >> 3);
  int split = 0, kt0 = 0, m0, n0;
  if (EPI == 3) {
    split = wg >> 6;                 // 4 K-splits of 16 tiles each
    int rem = wg & 63;               // 16 m-tiles x 4 n-tiles
    m0 = (rem & 15) << 8;
    n0 = (rem >> 4) << 8;
    kt0 = split << 4;
  } else {
    m0 = (wg & 15) << 8;             // M/256 == 16 for all uses here
    n0 = (wg >> 4) << 8;
  }
  const int gc = ((lane & 7) ^ (lane >> 3)) << 3;
  const int srow = wv * 8 + (lane >> 3);

  // lt = LOCAL tile index (0..15); global K-tile = kt0 + lt (kt0 even -> same
  // buffer parity as lt).
  auto stageA = [&](int lt, int h) {
    const _Float16* g = A + (size_t)(m0 + h * 128 + srow) * K + (kt0 + lt) * 64 + gc;
    _Float16* l = &lds[lt & 1][0][h][wv * 512];
    ld_lds16(g, l);
    ld_lds16(g + (size_t)64 * K, l + 4096);
  };
  auto stageB = [&](int lt, int h) {
    const _Float16* g = W + (size_t)(n0 + h * 128 + srow) * K + (kt0 + lt) * 64 + gc;
    _Float16* l = &lds[lt & 1][1][h][wv * 512];
    ld_lds16(g, l);
    ld_lds16(g + (size_t)64 * K, l + 4096);
  };
  auto rdf = [&](const _Float16* base, int fi, int ks) -> f16x8 {
    int row = fi * 16 + l16;
    int pc = ((ks << 2) + quad) ^ (l16 & 7);
    return *(const f16x8*)(base + row * 64 + (pc << 3));
  };

  f32x4 acc[8][4];
  const f32x4 zero = {0.f, 0.f, 0.f, 0.f};
  #pragma unroll
  for (int i = 0; i < 8; i++)
    #pragma unroll
    for (int j = 0; j < 4; j++) acc[i][j] = zero;
  f16x8 ar[4][2], br[4][2];

  stageA(0, 0); stageA(0, 1); stageB(0, 0); stageB(0, 1);
  stageB(1, 0); stageB(1, 1);
  asm volatile("s_waitcnt vmcnt(4)" ::: "memory");
  __builtin_amdgcn_s_barrier();

  const int NT = 16;            // 16 local K-tiles per block
  const int ITERS = NT >> 1;    // 8
  for (int it = 0; it < ITERS - 1; ++it) {
    const int t0 = it * 2;
    LDA(0, 0); LDB(0, 0); stageA(t0 + 1, 0);
    GPH_OPEN(); GMFMA(0, 0); GPH_CLOSE();
    LDB(0, 2); stageA(t0 + 1, 1);
    GPH_OPEN(); GMFMA(0, 2); GPH_CLOSE();
    LDA(0, 4); stageB(t0 + 2, 0);
    GPH_OPEN(); GMFMA(4, 0); GPH_CLOSE();
    stageB(t0 + 2, 1);
    GPH_OPEN(); GMFMA(4, 2); GPH_CLOSE_VM(4);
    LDA(1, 0); LDB(1, 0); stageA(t0 + 2, 0);
    GPH_OPEN(); GMFMA(0, 0); GPH_CLOSE();
    LDB(1, 2); stageA(t0 + 2, 1);
    GPH_OPEN(); GMFMA(0, 2); GPH_CLOSE();
    LDA(1, 4); stageB(t0 + 3, 0);
    GPH_OPEN(); GMFMA(4, 0); GPH_CLOSE();
    stageB(t0 + 3, 1);
    GPH_OPEN(); GMFMA(4, 2); GPH_CLOSE_VM(4);
  }
  {
    LDA(0, 0); LDB(0, 0); stageA(NT - 1, 0);
    GPH_OPEN(); GMFMA(0, 0); GPH_CLOSE();
    LDB(0, 2); stageA(NT - 1, 1);
    GPH_OPEN(); GMFMA(0, 2); GPH_CLOSE();
    LDA(0, 4);
    GPH_OPEN(); GMFMA(4, 0); GPH_CLOSE();
    GPH_OPEN(); GMFMA(4, 2); GPH_CLOSE_VM(0);
    LDA(1, 0); LDB(1, 0);
    GPH_OPEN(); GMFMA(0, 0); GPH_CLOSE();
    LDB(1, 2);
    GPH_OPEN(); GMFMA(0, 2); GPH_CLOSE();
    LDA(1, 4);
    GPH_OPEN(); GMFMA(4, 0); GPH_CLOSE();
    GPH_OPEN(); GMFMA(4, 2); GPH_CLOSE();
  }

  // epilogue
  _Float16* po = outB;
  if (EPI == 3)
    po = (split < 2 ? outB : outB2) + (size_t)(split & 1) * ((size_t)M * N);
  #pragma unroll
  for (int mi = 0; mi < 8; mi++) {
    int grow = m0 + wm * 128 + mi * 16 + quad * 4;
    #pragma unroll
    for (int ni = 0; ni < 4; ni++) {
      int gcol = n0 + wn * 64 + ni * 16 + l16;
      float bb = (EPI == 3) ? 0.f : bias[gcol];
      #pragma unroll
      for (int r = 0; r < 4; r++) {
        size_t oi = (size_t)(grow + r) * N + gcol;
        float c = acc[mi][ni][r] + bb;
        po[oi] = (_Float16)(EPI == 2 ? gelu_act(c) : c);
      }
    }
  }
}

// ---------------- fc2 combine: out = x1 + gamma2*(p0+p1+p2+p3 + bias) -------
__global__ __launch_bounds__(256) void fc2_combine(
    const _Float16* __restrict__ p01, const _Float16* __restrict__ p23,
    const float* __restrict__ x1, const float* __restrict__ gamma,
    const float* __restrict__ bias, float* __restrict__ out) {
  const size_t idx = ((size_t)blockIdx.x * 256 + threadIdx.x) * 4;
  const int col = (int)(idx & (D_ - 1));
  const size_t soff = (size_t)M_ * D_;
  f16x4 a = *(const f16x4*)(p01 + idx);
  f16x4 b = *(const f16x4*)(p01 + soff + idx);
  f16x4 c = *(const f16x4*)(p23 + idx);
  f16x4 d = *(const f16x4*)(p23 + soff + idx);
  float4 xv = *(const float4*)(x1 + idx);
  float4 gv = *(const float4*)(gamma + col);
  float4 bv = *(const float4*)(bias + col);
  float4 o;
  o.x = xv.x + gv.x * ((float)a[0] + (float)b[0] + (float)c[0] + (float)d[0] + bv.x);
  o.y = xv.y + gv.y * ((float)a[1] + (float)b[1] + (float)c[1] + (float)d[1] + bv.y);
  o.z = xv.z + gv.z * ((float)a[2] + (float)b[2] + (float)c[2] + (float)d[2] + bv.z);
  o.w = xv.w + gv.w * ((float)a[3] + (float)b[3] + (float)c[3] + (float)d[3] + bv.w);
  *(float4*)(out + idx) = o;
}

// ---------------- V transpose + bsum accumulation ----------------
// vt[b][h][d][j]; also bsum[b][h*64+d] += b2[h] * sum_j V[b,h,j,d]
__global__ __launch_bounds__(256) void transpose_v(const _Float16* __restrict__ qkv,
                                                   _Float16* __restrict__ vt,
                                                   const float* __restrict__ b2,
                                                   float* __restrict__ bsum) {
  int jt = blockIdx.x;
  int h = blockIdx.y;
  int b = blockIdx.z;
  __shared__ _Float16 tl[64][68];
  int tid = threadIdx.x;
  int j0 = jt * 64;
  #pragma unroll
  for (int k = 0; k < 16; k++) {
    int idx = k * 256 + tid;
    int jr = idx >> 6, dc = idx & 63;
    tl[jr][dc] = qkv[(size_t)(b * N_ + j0 + jr) * (3 * D_) + 2 * D_ + h * 64 + dc];
  }
  __syncthreads();
  #pragma unroll
  for (int k = 0; k < 16; k++) {
    int idx = k * 256 + tid;
    int dr = idx >> 6, jc = idx & 63;
    vt[(size_t)((b * H_ + h) * DH_ + dr) * N_ + j0 + jc] = tl[jc][dr];
  }
  int d = tid & 63, jq = tid >> 6;
  float s = 0.f;
  #pragma unroll
  for (int r = 0; r < 16; r++) s += (float)tl[jq * 16 + r][d];
  atomicAdd(&bsum[b * D_ + h * 64 + d], b2[h] * s);
}

// ---------------- Talking-heads attention (r6 loop; XCD-local decode) -------
// grid (4 b, 64 i-tiles): linear id = b + 4*it -> XCD = b + 4*(it&1), so each
// XCD serves ONE batch: K+V working set 4 MB = L2-fit. Inner loop = r6.
__global__ __launch_bounds__(1024, 4) void attn_th(
    const _Float16* __restrict__ qkv, const _Float16* __restrict__ vt,
    const _Float16* __restrict__ w1f, const _Float16* __restrict__ w2f,
    const float* __restrict__ b1f, const float* __restrict__ bsum,
    _Float16* __restrict__ ob) {
  __shared__ __align__(16) _Float16 SP[2 * 16512];  // S planes | P planes
  __shared__ float lsum[272];                       // [e][i] + pad (stride 17)
  _Float16* Sp = SP;
  _Float16* Pp = SP + 16512;

  const int tid = threadIdx.x;
  const int wave = tid >> 6;
  const int lane = tid & 63;
  const int quad = lane >> 4, l16 = lane & 15;
  const int i0 = blockIdx.y * 16;
  const int b = blockIdx.x;
  const size_t bN = (size_t)b * N_;
  const f32x4 zero = {0.f, 0.f, 0.f, 0.f};

  // Q fragments (head=wave), pre-scaled by DH^-1/2 = 0.125 (exact in f16)
  f16x8 qf[2];
  #pragma unroll
  for (int ks = 0; ks < 2; ks++) {
    f16x8 q = *(const f16x8*)(qkv + (bN + i0 + l16) * 3072 + wave * 64 + ks * 32 + quad * 8);
    #pragma unroll
    for (int e = 0; e < 8; e++) q[e] = q[e] * (_Float16)0.125f;
    qf[ks] = q;
  }
  // W1 B-fragment: B[k=h][n=e] = W1[e][h]
  f16x4 w1a = *(const f16x4*)(w1f + l16 * 16 + quad * 4);
  float b1v = b1f[l16];
  f32x4 b1i = {b1v, b1v, b1v, b1v};

  const _Float16* vbase = vt + (size_t)((b * H_ + wave) * DH_ + l16) * N_ + quad * 8;

  f32x4 uacc[4];
  #pragma unroll
  for (int nt = 0; nt < 4; nt++) uacc[nt] = zero;
  float lacc = 0.f;

  // K fragments for the current tile (reloaded in place each iteration)
  f16x8 kcur[4][2];
  auto loadK = [&](int j0) {
    #pragma unroll
    for (int jb = 0; jb < 4; jb++) {
      const _Float16* kb = qkv + (bN + j0 + jb * 16 + l16) * 3072 + 1024 + wave * 64 + quad * 8;
      kcur[jb][0] = *(const f16x8*)kb;
      kcur[jb][1] = *(const f16x8*)(kb + 32);
    }
  };
  loadK(0);

  f16x8 vreg[4];  // first 32-j half of V tile, prefetched

  for (int t = 0; t < 16; t++) {
    int j0 = t * 64;
    // ---- S = (QK^T)^T for head h=wave: C[m=j][n=i] -> S plane [h][i][j]
    f32x4 sres[4];
    #pragma unroll
    for (int jb = 0; jb < 4; jb++) {
      f32x4 s = __builtin_amdgcn_mfma_f32_16x16x32_f16(kcur[jb][0], qf[0], zero, 0, 0, 0);
      sres[jb] = __builtin_amdgcn_mfma_f32_16x16x32_f16(kcur[jb][1], qf[1], s, 0, 0, 0);
    }
    #pragma unroll
    for (int jb = 0; jb < 4; jb++) {
      f16x4 sv;
      #pragma unroll
      for (int r = 0; r < 4; r++) sv[r] = (_Float16)sres[jb][r];
      *(f16x4*)(Sp + lds_off(wave, l16, jb * 16 + quad * 4)) = sv;
    }
    // ---- prefetch next K tile (kcur dead after the MFMAs above) and this
    // tile's first V half; the barrier's vmcnt(0) drain makes them resident.
    if (t < 15) loadK(j0 + 64);
    #pragma unroll
    for (int nt = 0; nt < 4; nt++)
      vreg[nt] = *(const f16x8*)(vbase + (size_t)(nt * 16) * N_ + j0);
    __syncthreads();
    // ---- mix1 (row i=wave) -> exp (unnormalized) -> P planes + l accumulate
    #pragma unroll
    for (int cg = 0; cg < 4; cg++) {
      f16x4 sf;
      #pragma unroll
      for (int t4 = 0; t4 < 4; t4++)
        sf[t4] = Sp[lds_off(quad * 4 + t4, wave, cg * 16 + l16)];
      f32x4 a = __builtin_amdgcn_mfma_f32_16x16x16f16(sf, w1a, b1i, 0, 0, 0);
      f16x4 pv;
      #pragma unroll
      for (int r = 0; r < 4; r++) {
        float e = __expf(a[r]);
        lacc += e;
        pv[r] = (_Float16)e;
      }
      *(f16x4*)(Pp + lds_off(l16, wave, cg * 16 + quad * 4)) = pv;
    }
    __syncthreads();
    // ---- PV: U_e += V @ P_e^T (e=wave): C[m=d][n=i]
    f16x8 pf0 = *(const f16x8*)(Pp + lds_off(wave, l16, quad * 8));
    f16x8 pf1 = *(const f16x8*)(Pp + lds_off(wave, l16, 32 + quad * 8));
    #pragma unroll
    for (int nt = 0; nt < 4; nt++)
      uacc[nt] = __builtin_amdgcn_mfma_f32_16x16x32_f16(vreg[nt], pf0, uacc[nt], 0, 0, 0);
    #pragma unroll
    for (int nt = 0; nt < 4; nt++) {
      f16x8 vf = *(const f16x8*)(vbase + (size_t)(nt * 16) * N_ + j0 + 32);
      uacc[nt] = __builtin_amdgcn_mfma_f32_16x16x32_f16(vf, pf1, uacc[nt], 0, 0, 0);
    }
    // no barrier: next computeS writes S planes (disjoint from P); mix1(t+1)
    // writes P only after the next barrier.
  }

  // ---------------- epilogue ----------------
  lacc += __shfl_xor(lacc, 16);
  lacc += __shfl_xor(lacc, 32);
  __syncthreads();                       // all PV reads of P done
  if (quad == 0) lsum[l16 * 17 + wave] = lacc;
  __syncthreads();
  float invl = 1.0f / lsum[wave * 17 + l16];   // (e=wave, i=l16)

  _Float16* Uf = Sp;
  #pragma unroll
  for (int nt = 0; nt < 4; nt++) {
    f16x4 u;
    #pragma unroll
    for (int r = 0; r < 4; r++) u[r] = (_Float16)(uacc[nt][r] * invl);
    *(f16x4*)(Uf + wave * 1092 + l16 * 68 + nt * 16 + quad * 4) = u;
  }
  __syncthreads();

  f16x4 w2a = *(const f16x4*)(w2f + l16 * 16 + quad * 4);
  #pragma unroll
  for (int cg = 0; cg < 4; cg++) {
    f16x4 af;
    #pragma unroll
    for (int t4 = 0; t4 < 4; t4++)
      af[t4] = Uf[(quad * 4 + t4) * 1092 + wave * 68 + cg * 16 + l16];
    f32x4 o = __builtin_amdgcn_mfma_f32_16x16x16f16(af, w2a, zero, 0, 0, 0);
    f32x4 bs = *(const f32x4*)(bsum + b * D_ + l16 * 64 + cg * 16 + quad * 4);
    f16x4 ov;
    #pragma unroll
    for (int r = 0; r < 4; r++) ov[r] = (_Float16)(o[r] + bs[r]);
    *(f16x4*)(ob + (bN + i0 + wave) * D_ + l16 * 64 + cg * 16 + quad * 4) = ov;
  }
}

// ---------------------------------------------------------------------------
extern "C" void kernel_launch(void* const* d_in, const int* in_sizes, int n_in,
                              void* d_out, int out_size, void* d_ws, size_t ws_size,
                              hipStream_t stream) {
  const float* x      = (const float*)d_in[0];
  const float* ln1_w  = (const float*)d_in[1];
  const float* ln1_b  = (const float*)d_in[2];
  const float* qkv_w  = (const float*)d_in[3];
  const float* qkv_b  = (const float*)d_in[4];
  const float* plw    = (const float*)d_in[5];
  const float* plb    = (const float*)d_in[6];
  const float* pww    = (const float*)d_in[7];
  const float* pwb    = (const float*)d_in[8];
  const float* out_w  = (const float*)d_in[9];
  const float* out_b  = (const float*)d_in[10];
  const float* gamma1 = (const float*)d_in[11];
  const float* ln2_w  = (const float*)d_in[12];
  const float* ln2_b  = (const float*)d_in[13];
  const float* fc1_w  = (const float*)d_in[14];
  const float* fc1_b  = (const float*)d_in[15];
  const float* fc2_w  = (const float*)d_in[16];
  const float* fc2_b  = (const float*)d_in[17];
  const float* gamma2 = (const float*)d_in[18];
  float* out = (float*)d_out;

  char* ws = (char*)d_ws;
  _Float16* wq   = (_Float16*)(ws + 0);          // 6291456 B
  _Float16* wo   = (_Float16*)(ws + 6291456);    // 2097152 B
  _Float16* wf1  = (_Float16*)(ws + 8388608);    // 8388608 B (clean fc1 weights)
  _Float16* wf2  = (_Float16*)(ws + 16777216);   // 8388608 B
  float*    x1   = (float*)   (ws + 25165824);   // 16777216 B (first 17.4 KB host
                                                 //  mix tables/bsum during attn)
  _Float16* ob   = (_Float16*)(ws + 41943040);   // 8388608 B
  _Float16* hb   = (_Float16*)(ws + 50331648);   // 8388608 B
  _Float16* qkvb = (_Float16*)(ws + 58720256);   // 25165824 B
  _Float16* vtb  = (_Float16*)(ws + 83886080);   // 8388608 B
  _Float16* fb   = (_Float16*)(ws + 58720256);   // 33554432 B, aliases qkvb+vtb (dead by then)
  _Float16* w1f  = (_Float16*)(ws + 25165824);          // 512 B
  _Float16* w2f  = (_Float16*)(ws + 25165824 + 512);    // 512 B
  float*    bsum = (float*)   (ws + 25165824 + 1024);   // 16384 B
  // fc2 split-K partials (live only during fc2 gemm + combine):
  _Float16* p01  = (_Float16*)(ws + 0);          // 16777216 B over wq/wo/wf1 (dead)
  _Float16* p23  = (_Float16*)(ws + 41943040);   // 16777216 B over ob/hb (dead)
  if (ws_size < 92274688) return;

  cast_all<<<12289, 256, 0, stream>>>(qkv_w, wq, out_w, wo, fc1_w, wf1, fc2_w, wf2,
                                      plw, pww, w1f, w2f, bsum);

  ln_f16<<<4096, 256, 0, stream>>>(x, ln1_w, ln1_b, hb);
  gemm_nt8<0><<<192, 512, 0, stream>>>(hb, wq, qkv_b, M_, 3 * D_, D_, qkvb, nullptr);
  transpose_v<<<dim3(16, 16, 4), 256, 0, stream>>>(qkvb, vtb, pwb, bsum);
  attn_th<<<dim3(4, 64), 1024, 0, stream>>>(qkvb, vtb, w1f, w2f, plb, bsum, ob);
  gemm_nt<1, 64, 4, 1><<<dim3(32, 16), 256, 0, stream>>>(ob, wo, out_b, M_, D_, D_, nullptr, x1, x, gamma1);

  ln_f16<<<4096, 256, 0, stream>>>(x1, ln2_w, ln2_b, hb);
  gemm_nt8<2><<<256, 512, 0, stream>>>(hb, wf1, fc1_b, M_, FF_, D_, fb, nullptr);
  gemm_nt8<3><<<256, 512, 0, stream>>>(fb, wf2, fc2_b, M_, D_, FF_, p01, p23);
  fc2_combine<<<4096, 256, 0, stream>>>(p01, p23, x1, gamma2, fc2_b, out);
}

// Round 9
// 411.227 us; speedup vs baseline: 1.6295x; 1.0382x over previous
//
#include <hip/hip_runtime.h>

// ---------------------------------------------------------------------------
// SelfAttentionLayer (talking-heads) on MI355X gfx950. Round 15.
// r14 (427.0 us) + two safe increments:
//   * out-proj: BN=64 grid(32,16) -> BN=128/OCC=3 grid(32,8): 256 blocks =
//     exact fill, half B-staging, NI=4 (2x MFMA/phase), XCD-local A-strips.
//   * ln1 merged into cast_all (union grid 16385): independent memory-bound
//     work overlaps instead of serializing; one fewer dispatch.
//   * attn CLOSED at 131.5 us (unified-RF demand 128 regs/wave -> 1 blk/CU
//     structurally; r11 spill explained). fc2 split-K kept (r14: -22 us).
// ---------------------------------------------------------------------------

typedef _Float16 f16x8 __attribute__((ext_vector_type(8)));
typedef _Float16 f16x4 __attribute__((ext_vector_type(4)));
typedef _Float16 f16x2 __attribute__((ext_vector_type(2)));
typedef float f32x4 __attribute__((ext_vector_type(4)));

#define B_ 4
#define N_ 1024
#define D_ 1024
#define H_ 16
#define DH_ 64
#define FF_ 4096
#define M_ (B_ * N_)

__device__ __forceinline__ float gelu_act(float x) {
  float z = 0.7978845608028654f * (x + 0.044715f * x * x * x);
  return x / (1.0f + __expf(-2.0f * z));
}

__device__ __forceinline__ void ld_lds16(const _Float16* g, _Float16* l) {
  __builtin_amdgcn_global_load_lds((const __attribute__((address_space(1))) void*)g,
                                   (__attribute__((address_space(3))) void*)l, 16, 0, 0);
}

__device__ __forceinline__ int swz8(int i) {
  return (((i >> 2) << 1) ^ (i & 3)) & 7;
}
// S/P plane addressing (v4/v5-proven): plane p stride 1032 f16, row i (64 f16),
// col j chunk-swizzled. mix1 u16 gathers, b64 writes, b128 PV reads <=2-way.
__device__ __forceinline__ int lds_off(int p, int i, int j) {
  int ch = ((j >> 3) ^ swz8(i) ^ ((p >> 2) << 1)) & 7;
  return p * 1032 + i * 64 + (ch << 3) + (j & 7);
}

// ---------------- fused prep: 4 casts + tables + bsum zero + ln1 ----------
// blocks 0..12287: f32->f16 weight casts. block 12288: mix tables + bsum=0.
// blocks 12289..16384: LayerNorm1 row (b-12289) of x -> hb (independent work
// merged so its BW overlaps the casts instead of serializing).
__global__ __launch_bounds__(256) void cast_all(
    const float* __restrict__ a0, _Float16* __restrict__ o0,   // qkv_w  3072*1024
    const float* __restrict__ a1, _Float16* __restrict__ o1,   // out_w  1024*1024
    const float* __restrict__ a2, _Float16* __restrict__ o2,   // fc1_w  4096*1024
    const float* __restrict__ a3, _Float16* __restrict__ o3,   // fc2_w  1024*4096
    const float* __restrict__ W1, const float* __restrict__ W2,
    _Float16* __restrict__ w1f, _Float16* __restrict__ w2f,
    float* __restrict__ bsum,
    const float* __restrict__ x, const float* __restrict__ ln_w,
    const float* __restrict__ ln_b, _Float16* __restrict__ hb) {
  int b = blockIdx.x, t = threadIdx.x;
  if (b >= 12289) {  // ---- LayerNorm1 branch ----
    int row = b - 12289;
    const float* xr = x + (size_t)row * D_;
    float4 v = *(const float4*)(xr + t * 4);
    float s = v.x + v.y + v.z + v.w;
    float sq = v.x * v.x + v.y * v.y + v.z * v.z + v.w * v.w;
    #pragma unroll
    for (int off = 32; off > 0; off >>= 1) {
      s += __shfl_down(s, off);
      sq += __shfl_down(sq, off);
    }
    __shared__ float red[8];
    int wave = t >> 6, lane = t & 63;
    if (lane == 0) { red[wave] = s; red[4 + wave] = sq; }
    __syncthreads();
    float ts = red[0] + red[1] + red[2] + red[3];
    float tq = red[4] + red[5] + red[6] + red[7];
    float mean = ts * (1.0f / (float)D_);
    float var = tq * (1.0f / (float)D_) - mean * mean;
    float rs = rsqrtf(var + 1e-5f);
    float4 wv = *(const float4*)(ln_w + t * 4);
    float4 bv = *(const float4*)(ln_b + t * 4);
    f16x4 o;
    o[0] = (_Float16)((v.x - mean) * rs * wv.x + bv.x);
    o[1] = (_Float16)((v.y - mean) * rs * wv.y + bv.y);
    o[2] = (_Float16)((v.z - mean) * rs * wv.z + bv.z);
    o[3] = (_Float16)((v.w - mean) * rs * wv.w + bv.w);
    *(f16x4*)(hb + (size_t)row * D_ + t * 4) = o;
    return;
  }
  const float* in;
  _Float16* out;
  int base;
  if (b < 3072) { in = a0; out = o0; base = b; }
  else if (b < 4096) { in = a1; out = o1; base = b - 3072; }
  else if (b < 8192) { in = a2; out = o2; base = b - 4096; }
  else if (b < 12288) { in = a3; out = o3; base = b - 8192; }
  else {
    w1f[t] = (_Float16)W1[t];
    w2f[t] = (_Float16)W2[t];
    float4 z = {0.f, 0.f, 0.f, 0.f};
    #pragma unroll
    for (int r = 0; r < 4; r++) *(float4*)(bsum + t * 16 + r * 4) = z;
    return;
  }
  int i = (base * 256 + t) * 4;
  float4 v = *(const float4*)(in + i);
  f16x4 o;
  o[0] = (_Float16)v.x; o[1] = (_Float16)v.y; o[2] = (_Float16)v.z; o[3] = (_Float16)v.w;
  *(f16x4*)(out + i) = o;
}

// ---------------- LayerNorm (row of 1024) -> fp16 (ln2) ----------------
__global__ __launch_bounds__(256) void ln_f16(const float* __restrict__ x,
                                              const float* __restrict__ w,
                                              const float* __restrict__ b,
                                              _Float16* __restrict__ out) {
  int row = blockIdx.x;
  int tid = threadIdx.x;
  const float* xr = x + (size_t)row * D_;
  float4 v = *(const float4*)(xr + tid * 4);
  float s = v.x + v.y + v.z + v.w;
  float sq = v.x * v.x + v.y * v.y + v.z * v.z + v.w * v.w;
  #pragma unroll
  for (int off = 32; off > 0; off >>= 1) {
    s += __shfl_down(s, off);
    sq += __shfl_down(sq, off);
  }
  __shared__ float red[8];
  int wave = tid >> 6, lane = tid & 63;
  if (lane == 0) { red[wave] = s; red[4 + wave] = sq; }
  __syncthreads();
  float ts = red[0] + red[1] + red[2] + red[3];
  float tq = red[4] + red[5] + red[6] + red[7];
  float mean = ts * (1.0f / (float)D_);
  float var = tq * (1.0f / (float)D_) - mean * mean;
  float rs = rsqrtf(var + 1e-5f);
  float4 wv = *(const float4*)(w + tid * 4);
  float4 bv = *(const float4*)(b + tid * 4);
  f16x4 o;
  o[0] = (_Float16)((v.x - mean) * rs * wv.x + bv.x);
  o[1] = (_Float16)((v.y - mean) * rs * wv.y + bv.y);
  o[2] = (_Float16)((v.z - mean) * rs * wv.z + bv.z);
  o[3] = (_Float16)((v.w - mean) * rs * wv.w + bv.w);
  *(f16x4*)(out + (size_t)row * D_ + tid * 4) = o;
}

// ---------------- NT GEMM (128-tile, 2-barrier): out-proj ----------------
// SWAPXY=1: blockIdx.x indexes M-tiles (XCD owns m-strips -> A rows L2-local).
template <int EPI, int BN, int OCC, int SWAPXY>
__global__ __launch_bounds__(256, OCC) void gemm_nt(
    const _Float16* __restrict__ A, const _Float16* __restrict__ W,
    const float* __restrict__ bias, int M, int N, int K,
    _Float16* __restrict__ outB, float* __restrict__ outF,
    const float* __restrict__ res, const float* __restrict__ gamma) {
  __shared__ _Float16 As[128 * 64];
  __shared__ _Float16 Bs[BN * 64];
  int tid = threadIdx.x;
  int wave = tid >> 6, lane = tid & 63;
  int quad = lane >> 4, l16 = lane & 15;
  int wm = wave >> 1, wn = wave & 1;
  int m0 = (SWAPXY ? blockIdx.x : blockIdx.y) * 128;
  int n0 = (SWAPXY ? blockIdx.y : blockIdx.x) * BN;
  int lrow = lane >> 3, lcol = (lane & 7) * 8;
  const int NI = (BN == 128) ? 4 : 2;
  const int WN = (BN == 128) ? 64 : 32;

  f32x4 zero = {0.f, 0.f, 0.f, 0.f};
  f32x4 acc[4][NI];
  #pragma unroll
  for (int i = 0; i < 4; i++)
    #pragma unroll
    for (int j = 0; j < NI; j++) acc[i][j] = zero;

  for (int k0 = 0; k0 < K; k0 += 64) {
    __syncthreads();
    #pragma unroll
    for (int c = 0; c < 4; c++) {
      int rb = c * 32 + wave * 8;
      ld_lds16(A + (size_t)(m0 + rb + lrow) * K + k0 + lcol, As + rb * 64);
      if (BN == 128 || c < 2)
        ld_lds16(W + (size_t)(n0 + rb + lrow) * K + k0 + lcol, Bs + rb * 64);
    }
    __syncthreads();
    #pragma unroll
    for (int ks = 0; ks < 2; ks++) {
      int kk = ks * 32 + quad * 8;
      f16x8 a[4], bfr[NI];
      #pragma unroll
      for (int i = 0; i < 4; i++) a[i] = *(const f16x8*)(As + (wm * 64 + i * 16 + l16) * 64 + kk);
      #pragma unroll
      for (int i = 0; i < NI; i++) bfr[i] = *(const f16x8*)(Bs + (wn * WN + i * 16 + l16) * 64 + kk);
      #pragma unroll
      for (int mi = 0; mi < 4; mi++)
        #pragma unroll
        for (int ni = 0; ni < NI; ni++)
          acc[mi][ni] = __builtin_amdgcn_mfma_f32_16x16x32_f16(a[mi], bfr[ni], acc[mi][ni], 0, 0, 0);
    }
  }

  #pragma unroll
  for (int mi = 0; mi < 4; mi++) {
    int grow_base = m0 + wm * 64 + mi * 16 + quad * 4;
    #pragma unroll
    for (int ni = 0; ni < NI; ni++) {
      int gcol = n0 + wn * WN + ni * 16 + l16;
      float bb = bias[gcol];
      float gm = (EPI == 1) ? gamma[gcol] : 0.f;
      #pragma unroll
      for (int r = 0; r < 4; r++) {
        size_t oi = (size_t)(grow_base + r) * N + gcol;
        float c = acc[mi][ni][r] + bb;
        if (EPI == 0) {
          outB[oi] = (_Float16)c;
        } else if (EPI == 1) {
          outF[oi] = res[oi] + gm * c;
        } else {
          outB[oi] = (_Float16)gelu_act(c);
        }
      }
    }
  }
}

// ---------------- 8-phase 256x256 NT GEMM ----------------
// EPI 0: plain f16 out (qkv). EPI 2: gelu f16 out (fc1). Both: K=1024 full.
// EPI 3: split-K partial (fc2): grid = 64 tile-positions x 4 splits; each
// split runs the identical 16-tile K=1024 schedule at kt offset split*16 and
// writes f16 partials (no bias) to (split<2?outB:outB2)+(split&1)*M*N.
#define GPH_OPEN()                                      \
  __builtin_amdgcn_sched_barrier(0);                    \
  __builtin_amdgcn_s_barrier();                         \
  asm volatile("s_waitcnt lgkmcnt(0)" ::: "memory");    \
  __builtin_amdgcn_sched_barrier(0);                    \
  __builtin_amdgcn_s_setprio(1)

#define GPH_CLOSE()                                     \
  __builtin_amdgcn_s_setprio(0);                        \
  __builtin_amdgcn_sched_barrier(0);                    \
  __builtin_amdgcn_s_barrier()

#define GPH_CLOSE_VM(n)                                 \
  __builtin_amdgcn_s_setprio(0);                        \
  __builtin_amdgcn_sched_barrier(0);                    \
  asm volatile("s_waitcnt vmcnt(" #n ")" ::: "memory"); \
  __builtin_amdgcn_s_barrier()

#define GMFMA(MB, NB)                                                         \
  _Pragma("unroll") for (int ks = 0; ks < 2; ks++)                            \
  _Pragma("unroll") for (int mi = 0; mi < 4; mi++)                            \
  _Pragma("unroll") for (int ni = 0; ni < 2; ni++)                            \
    acc[MB + mi][NB + ni] = __builtin_amdgcn_mfma_f32_16x16x32_f16(           \
        ar[mi][ks], br[NB + ni][ks], acc[MB + mi][NB + ni], 0, 0, 0)

#define LDA(buf, MB)                                            \
  _Pragma("unroll") for (int ks = 0; ks < 2; ks++)              \
  _Pragma("unroll") for (int mi = 0; mi < 4; mi++)              \
    ar[mi][ks] = rdf(&lds[buf][0][wm][0], MB + mi, ks)

#define LDB(buf, NB)                                            \
  _Pragma("unroll") for (int ks = 0; ks < 2; ks++)              \
  _Pragma("unroll") for (int ni = 0; ni < 2; ni++)              \
    br[NB + ni][ks] = rdf(&lds[buf][1][wn >> 1][0], fbB + NB + ni, ks)

template <int EPI>
__global__ __launch_bounds__(512, 2) void gemm_nt8(
    const _Float16* __restrict__ A, const _Float16* __restrict__ W,
    const float* __restrict__ bias, int M, int N, int K,
    _Float16* __restrict__ outB, _Float16* __restrict__ outB2) {
  __shared__ _Float16 lds[2][2][2][8192];  // [buf][A=0/B=1][row-half][128*64]
  const int tid = threadIdx.x;
  const int wv = tid >> 6, lane = tid & 63;
  const int quad = lane >> 4, l16 = lane & 15;
  const int wm = wv >> 2, wn = wv & 3;
  const int fbB = (wn & 1) * 4;
  const int wg = ((int)blockIdx.x & 7) * ((int)gridDim.x >> 3) + ((int)blockIdx.x >> 3);
  int split = 0, kt0 = 0, m0, n0;
  if (EPI == 3) {
    split = wg >> 6;                 // 4 K-splits of 16 tiles each
    int rem = wg & 63;               // 16 m-tiles x 4 n-tiles
    m0 = (rem & 15) << 8;
    n0 = (rem >> 4) << 8;
    kt0 = split << 4;
  } else {
    m0 = (wg & 15) << 8;             // M/256 == 16 for all uses here
    n0 = (wg >> 4) << 8;
  }
  const int gc = ((lane & 7) ^ (lane >> 3)) << 3;
  const int srow = wv * 8 + (lane >> 3);

  // lt = LOCAL tile index (0..15); global K-tile = kt0 + lt (kt0 even -> same
  // buffer parity as lt).
  auto stageA = [&](int lt, int h) {
    const _Float16* g = A + (size_t)(m0 + h * 128 + srow) * K + (kt0 + lt) * 64 + gc;
    _Float16* l = &lds[lt & 1][0][h][wv * 512];
    ld_lds16(g, l);
    ld_lds16(g + (size_t)64 * K, l + 4096);
  };
  auto stageB = [&](int lt, int h) {
    const _Float16* g = W + (size_t)(n0 + h * 128 + srow) * K + (kt0 + lt) * 64 + gc;
    _Float16* l = &lds[lt & 1][1][h][wv * 512];
    ld_lds16(g, l);
    ld_lds16(g + (size_t)64 * K, l + 4096);
  };
  auto rdf = [&](const _Float16* base, int fi, int ks) -> f16x8 {
    int row = fi * 16 + l16;
    int pc = ((ks << 2) + quad) ^ (l16 & 7);
    return *(const f16x8*)(base + row * 64 + (pc << 3));
  };

  f32x4 acc[8][4];
  const f32x4 zero = {0.f, 0.f, 0.f, 0.f};
  #pragma unroll
  for (int i = 0; i < 8; i++)
    #pragma unroll
    for (int j = 0; j < 4; j++) acc[i][j] = zero;
  f16x8 ar[4][2], br[4][2];

  stageA(0, 0); stageA(0, 1); stageB(0, 0); stageB(0, 1);
  stageB(1, 0); stageB(1, 1);
  asm volatile("s_waitcnt vmcnt(4)" ::: "memory");
  __builtin_amdgcn_s_barrier();

  const int NT = 16;            // 16 local K-tiles per block
  const int ITERS = NT >> 1;    // 8
  for (int it = 0; it < ITERS - 1; ++it) {
    const int t0 = it * 2;
    LDA(0, 0); LDB(0, 0); stageA(t0 + 1, 0);
    GPH_OPEN(); GMFMA(0, 0); GPH_CLOSE();
    LDB(0, 2); stageA(t0 + 1, 1);
    GPH_OPEN(); GMFMA(0, 2); GPH_CLOSE();
    LDA(0, 4); stageB(t0 + 2, 0);
    GPH_OPEN(); GMFMA(4, 0); GPH_CLOSE();
    stageB(t0 + 2, 1);
    GPH_OPEN(); GMFMA(4, 2); GPH_CLOSE_VM(4);
    LDA(1, 0); LDB(1, 0); stageA(t0 + 2, 0);
    GPH_OPEN(); GMFMA(0, 0); GPH_CLOSE();
    LDB(1, 2); stageA(t0 + 2, 1);
    GPH_OPEN(); GMFMA(0, 2); GPH_CLOSE();
    LDA(1, 4); stageB(t0 + 3, 0);
    GPH_OPEN(); GMFMA(4, 0); GPH_CLOSE();
    stageB(t0 + 3, 1);
    GPH_OPEN(); GMFMA(4, 2); GPH_CLOSE_VM(4);
  }
  {
    LDA(0, 0); LDB(0, 0); stageA(NT - 1, 0);
    GPH_OPEN(); GMFMA(0, 0); GPH_CLOSE();
    LDB(0, 2); stageA(NT - 1, 1);
    GPH_OPEN(); GMFMA(0, 2); GPH_CLOSE();
    LDA(0, 4);
    GPH_OPEN(); GMFMA(4, 0); GPH_CLOSE();
    GPH_OPEN(); GMFMA(4, 2); GPH_CLOSE_VM(0);
    LDA(1, 0); LDB(1, 0);
    GPH_OPEN(); GMFMA(0, 0); GPH_CLOSE();
    LDB(1, 2);
    GPH_OPEN(); GMFMA(0, 2); GPH_CLOSE();
    LDA(1, 4);
    GPH_OPEN(); GMFMA(4, 0); GPH_CLOSE();
    GPH_OPEN(); GMFMA(4, 2); GPH_CLOSE();
  }

  // epilogue
  _Float16* po = outB;
  if (EPI == 3)
    po = (split < 2 ? outB : outB2) + (size_t)(split & 1) * ((size_t)M * N);
  #pragma unroll
  for (int mi = 0; mi < 8; mi++) {
    int grow = m0 + wm * 128 + mi * 16 + quad * 4;
    #pragma unroll
    for (int ni = 0; ni < 4; ni++) {
      int gcol = n0 + wn * 64 + ni * 16 + l16;
      float bb = (EPI == 3) ? 0.f : bias[gcol];
      #pragma unroll
      for (int r = 0; r < 4; r++) {
        size_t oi = (size_t)(grow + r) * N + gcol;
        float c = acc[mi][ni][r] + bb;
        po[oi] = (_Float16)(EPI == 2 ? gelu_act(c) : c);
      }
    }
  }
}

// ---------------- fc2 combine: out = x1 + gamma2*(p0+p1+p2+p3 + bias) -------
__global__ __launch_bounds__(256) void fc2_combine(
    const _Float16* __restrict__ p01, const _Float16* __restrict__ p23,
    const float* __restrict__ x1, const float* __restrict__ gamma,
    const float* __restrict__ bias, float* __restrict__ out) {
  const size_t idx = ((size_t)blockIdx.x * 256 + threadIdx.x) * 4;
  const int col = (int)(idx & (D_ - 1));
  const size_t soff = (size_t)M_ * D_;
  f16x4 a = *(const f16x4*)(p01 + idx);
  f16x4 b = *(const f16x4*)(p01 + soff + idx);
  f16x4 c = *(const f16x4*)(p23 + idx);
  f16x4 d = *(const f16x4*)(p23 + soff + idx);
  float4 xv = *(const float4*)(x1 + idx);
  float4 gv = *(const float4*)(gamma + col);
  float4 bv = *(const float4*)(bias + col);
  float4 o;
  o.x = xv.x + gv.x * ((float)a[0] + (float)b[0] + (float)c[0] + (float)d[0] + bv.x);
  o.y = xv.y + gv.y * ((float)a[1] + (float)b[1] + (float)c[1] + (float)d[1] + bv.y);
  o.z = xv.z + gv.z * ((float)a[2] + (float)b[2] + (float)c[2] + (float)d[2] + bv.z);
  o.w = xv.w + gv.w * ((float)a[3] + (float)b[3] + (float)c[3] + (float)d[3] + bv.w);
  *(float4*)(out + idx) = o;
}

// ---------------- V transpose + bsum accumulation ----------------
// vt[b][h][d][j]; also bsum[b][h*64+d] += b2[h] * sum_j V[b,h,j,d]
__global__ __launch_bounds__(256) void transpose_v(const _Float16* __restrict__ qkv,
                                                   _Float16* __restrict__ vt,
                                                   const float* __restrict__ b2,
                                                   float* __restrict__ bsum) {
  int jt = blockIdx.x;
  int h = blockIdx.y;
  int b = blockIdx.z;
  __shared__ _Float16 tl[64][68];
  int tid = threadIdx.x;
  int j0 = jt * 64;
  #pragma unroll
  for (int k = 0; k < 16; k++) {
    int idx = k * 256 + tid;
    int jr = idx >> 6, dc = idx & 63;
    tl[jr][dc] = qkv[(size_t)(b * N_ + j0 + jr) * (3 * D_) + 2 * D_ + h * 64 + dc];
  }
  __syncthreads();
  #pragma unroll
  for (int k = 0; k < 16; k++) {
    int idx = k * 256 + tid;
    int dr = idx >> 6, jc = idx & 63;
    vt[(size_t)((b * H_ + h) * DH_ + dr) * N_ + j0 + jc] = tl[jc][dr];
  }
  int d = tid & 63, jq = tid >> 6;
  float s = 0.f;
  #pragma unroll
  for (int r = 0; r < 16; r++) s += (float)tl[jq * 16 + r][d];
  atomicAdd(&bsum[b * D_ + h * 64 + d], b2[h] * s);
}

// ---------------- Talking-heads attention (r6 loop; XCD-local decode) -------
// grid (4 b, 64 i-tiles): linear id = b + 4*it -> XCD = b + 4*(it&1), so each
// XCD serves ONE batch: K+V working set 4 MB = L2-fit. Inner loop = r6.
__global__ __launch_bounds__(1024, 4) void attn_th(
    const _Float16* __restrict__ qkv, const _Float16* __restrict__ vt,
    const _Float16* __restrict__ w1f, const _Float16* __restrict__ w2f,
    const float* __restrict__ b1f, const float* __restrict__ bsum,
    _Float16* __restrict__ ob) {
  __shared__ __align__(16) _Float16 SP[2 * 16512];  // S planes | P planes
  __shared__ float lsum[272];                       // [e][i] + pad (stride 17)
  _Float16* Sp = SP;
  _Float16* Pp = SP + 16512;

  const int tid = threadIdx.x;
  const int wave = tid >> 6;
  const int lane = tid & 63;
  const int quad = lane >> 4, l16 = lane & 15;
  const int i0 = blockIdx.y * 16;
  const int b = blockIdx.x;
  const size_t bN = (size_t)b * N_;
  const f32x4 zero = {0.f, 0.f, 0.f, 0.f};

  // Q fragments (head=wave), pre-scaled by DH^-1/2 = 0.125 (exact in f16)
  f16x8 qf[2];
  #pragma unroll
  for (int ks = 0; ks < 2; ks++) {
    f16x8 q = *(const f16x8*)(qkv + (bN + i0 + l16) * 3072 + wave * 64 + ks * 32 + quad * 8);
    #pragma unroll
    for (int e = 0; e < 8; e++) q[e] = q[e] * (_Float16)0.125f;
    qf[ks] = q;
  }
  // W1 B-fragment: B[k=h][n=e] = W1[e][h]
  f16x4 w1a = *(const f16x4*)(w1f + l16 * 16 + quad * 4);
  float b1v = b1f[l16];
  f32x4 b1i = {b1v, b1v, b1v, b1v};

  const _Float16* vbase = vt + (size_t)((b * H_ + wave) * DH_ + l16) * N_ + quad * 8;

  f32x4 uacc[4];
  #pragma unroll
  for (int nt = 0; nt < 4; nt++) uacc[nt] = zero;
  float lacc = 0.f;

  // K fragments for the current tile (reloaded in place each iteration)
  f16x8 kcur[4][2];
  auto loadK = [&](int j0) {
    #pragma unroll
    for (int jb = 0; jb < 4; jb++) {
      const _Float16* kb = qkv + (bN + j0 + jb * 16 + l16) * 3072 + 1024 + wave * 64 + quad * 8;
      kcur[jb][0] = *(const f16x8*)kb;
      kcur[jb][1] = *(const f16x8*)(kb + 32);
    }
  };
  loadK(0);

  f16x8 vreg[4];  // first 32-j half of V tile, prefetched

  for (int t = 0; t < 16; t++) {
    int j0 = t * 64;
    // ---- S = (QK^T)^T for head h=wave: C[m=j][n=i] -> S plane [h][i][j]
    f32x4 sres[4];
    #pragma unroll
    for (int jb = 0; jb < 4; jb++) {
      f32x4 s = __builtin_amdgcn_mfma_f32_16x16x32_f16(kcur[jb][0], qf[0], zero, 0, 0, 0);
      sres[jb] = __builtin_amdgcn_mfma_f32_16x16x32_f16(kcur[jb][1], qf[1], s, 0, 0, 0);
    }
    #pragma unroll
    for (int jb = 0; jb < 4; jb++) {
      f16x4 sv;
      #pragma unroll
      for (int r = 0; r < 4; r++) sv[r] = (_Float16)sres[jb][r];
      *(f16x4*)(Sp + lds_off(wave, l16, jb * 16 + quad * 4)) = sv;
    }
    // ---- prefetch next K tile (kcur dead after the MFMAs above) and this
    // tile's first V half; the barrier's vmcnt(0) drain makes them resident.
    if (t < 15) loadK(j0 + 64);
    #pragma unroll
    for (int nt = 0; nt < 4; nt++)
      vreg[nt] = *(const f16x8*)(vbase + (size_t)(nt * 16) * N_ + j0);
    __syncthreads();
    // ---- mix1 (row i=wave) -> exp (unnormalized) -> P planes + l accumulate
    #pragma unroll
    for (int cg = 0; cg < 4; cg++) {
      f16x4 sf;
      #pragma unroll
      for (int t4 = 0; t4 < 4; t4++)
        sf[t4] = Sp[lds_off(quad * 4 + t4, wave, cg * 16 + l16)];
      f32x4 a = __builtin_amdgcn_mfma_f32_16x16x16f16(sf, w1a, b1i, 0, 0, 0);
      f16x4 pv;
      #pragma unroll
      for (int r = 0; r < 4; r++) {
        float e = __expf(a[r]);
        lacc += e;
        pv[r] = (_Float16)e;
      }
      *(f16x4*)(Pp + lds_off(l16, wave, cg * 16 + quad * 4)) = pv;
    }
    __syncthreads();
    // ---- PV: U_e += V @ P_e^T (e=wave): C[m=d][n=i]
    f16x8 pf0 = *(const f16x8*)(Pp + lds_off(wave, l16, quad * 8));
    f16x8 pf1 = *(const f16x8*)(Pp + lds_off(wave, l16, 32 + quad * 8));
    #pragma unroll
    for (int nt = 0; nt < 4; nt++)
      uacc[nt] = __builtin_amdgcn_mfma_f32_16x16x32_f16(vreg[nt], pf0, uacc[nt], 0, 0, 0);
    #pragma unroll
    for (int nt = 0; nt < 4; nt++) {
      f16x8 vf = *(const f16x8*)(vbase + (size_t)(nt * 16) * N_ + j0 + 32);
      uacc[nt] = __builtin_amdgcn_mfma_f32_16x16x32_f16(vf, pf1, uacc[nt], 0, 0, 0);
    }
    // no barrier: next computeS writes S planes (disjoint from P); mix1(t+1)
    // writes P only after the next barrier.
  }

  // ---------------- epilogue ----------------
  lacc += __shfl_xor(lacc, 16);
  lacc += __shfl_xor(lacc, 32);
  __syncthreads();                       // all PV reads of P done
  if (quad == 0) lsum[l16 * 17 + wave] = lacc;
  __syncthreads();
  float invl = 1.0f / lsum[wave * 17 + l16];   // (e=wave, i=l16)

  _Float16* Uf = Sp;
  #pragma unroll
  for (int nt = 0; nt < 4; nt++) {
    f16x4 u;
    #pragma unroll
    for (int r = 0; r < 4; r++) u[r] = (_Float16)(uacc[nt][r] * invl);
    *(f16x4*)(Uf + wave * 1092 + l16 * 68 + nt * 16 + quad * 4) = u;
  }
  __syncthreads();

  f16x4 w2a = *(const f16x4*)(w2f + l16 * 16 + quad * 4);
  #pragma unroll
  for (int cg = 0; cg < 4; cg++) {
    f16x4 af;
    #pragma unroll
    for (int t4 = 0; t4 < 4; t4++)
      af[t4] = Uf[(quad * 4 + t4) * 1092 + wave * 68 + cg * 16 + l16];
    f32x4 o = __builtin_amdgcn_mfma_f32_16x16x16f16(af, w2a, zero, 0, 0, 0);
    f32x4 bs = *(const f32x4*)(bsum + b * D_ + l16 * 64 + cg * 16 + quad * 4);
    f16x4 ov;
    #pragma unroll
    for (int r = 0; r < 4; r++) ov[r] = (_Float16)(o[r] + bs[r]);
    *(f16x4*)(ob + (bN + i0 + wave) * D_ + l16 * 64 + cg * 16 + quad * 4) = ov;
  }
}

// ---------------------------------------------------------------------------
extern "C" void kernel_launch(void* const* d_in, const int* in_sizes, int n_in,
                              void* d_out, int out_size, void* d_ws, size_t ws_size,
                              hipStream_t stream) {
  const float* x      = (const float*)d_in[0];
  const float* ln1_w  = (const float*)d_in[1];
  const float* ln1_b  = (const float*)d_in[2];
  const float* qkv_w  = (const float*)d_in[3];
  const float* qkv_b  = (const float*)d_in[4];
  const float* plw    = (const float*)d_in[5];
  const float* plb    = (const float*)d_in[6];
  const float* pww    = (const float*)d_in[7];
  const float* pwb    = (const float*)d_in[8];
  const float* out_w  = (const float*)d_in[9];
  const float* out_b  = (const float*)d_in[10];
  const float* gamma1 = (const float*)d_in[11];
  const float* ln2_w  = (const float*)d_in[12];
  const float* ln2_b  = (const float*)d_in[13];
  const float* fc1_w  = (const float*)d_in[14];
  const float* fc1_b  = (const float*)d_in[15];
  const float* fc2_w  = (const float*)d_in[16];
  const float* fc2_b  = (const float*)d_in[17];
  const float* gamma2 = (const float*)d_in[18];
  float* out = (float*)d_out;

  char* ws = (char*)d_ws;
  _Float16* wq   = (_Float16*)(ws + 0);          // 6291456 B
  _Float16* wo   = (_Float16*)(ws + 6291456);    // 2097152 B
  _Float16* wf1  = (_Float16*)(ws + 8388608);    // 8388608 B (clean fc1 weights)
  _Float16* wf2  = (_Float16*)(ws + 16777216);   // 8388608 B
  float*    x1   = (float*)   (ws + 25165824);   // 16777216 B (first 17.4 KB host
                                                 //  mix tables/bsum during attn)
  _Float16* ob   = (_Float16*)(ws + 41943040);   // 8388608 B
  _Float16* hb   = (_Float16*)(ws + 50331648);   // 8388608 B
  _Float16* qkvb = (_Float16*)(ws + 58720256);   // 25165824 B
  _Float16* vtb  = (_Float16*)(ws + 83886080);   // 8388608 B
  _Float16* fb   = (_Float16*)(ws + 58720256);   // 33554432 B, aliases qkvb+vtb (dead by then)
  _Float16* w1f  = (_Float16*)(ws + 25165824);          // 512 B
  _Float16* w2f  = (_Float16*)(ws + 25165824 + 512);    // 512 B
  float*    bsum = (float*)   (ws + 25165824 + 1024);   // 16384 B
  // fc2 split-K partials (live only during fc2 gemm + combine):
  _Float16* p01  = (_Float16*)(ws + 0);          // 16777216 B over wq/wo/wf1 (dead)
  _Float16* p23  = (_Float16*)(ws + 41943040);   // 16777216 B over ob/hb (dead)
  if (ws_size < 92274688) return;

  cast_all<<<16385, 256, 0, stream>>>(qkv_w, wq, out_w, wo, fc1_w, wf1, fc2_w, wf2,
                                      plw, pww, w1f, w2f, bsum,
                                      x, ln1_w, ln1_b, hb);

  gemm_nt8<0><<<192, 512, 0, stream>>>(hb, wq, qkv_b, M_, 3 * D_, D_, qkvb, nullptr);
  transpose_v<<<dim3(16, 16, 4), 256, 0, stream>>>(qkvb, vtb, pwb, bsum);
  attn_th<<<dim3(4, 64), 1024, 0, stream>>>(qkvb, vtb, w1f, w2f, plb, bsum, ob);
  gemm_nt<1, 128, 3, 1><<<dim3(32, 8), 256, 0, stream>>>(ob, wo, out_b, M_, D_, D_, nullptr, x1, x, gamma1);

  ln_f16<<<4096, 256, 0, stream>>>(x1, ln2_w, ln2_b, hb);
  gemm_nt8<2><<<256, 512, 0, stream>>>(hb, wf1, fc1_b, M_, FF_, D_, fb, nullptr);
  gemm_nt8<3><<<256, 512, 0, stream>>>(fb, wf2, fc2_b, M_, D_, FF_, p01, p23);
  fc2_combine<<<4096, 256, 0, stream>>>(p01, p23, x1, gamma2, fc2_b, out);
}

// Round 10
// 405.103 us; speedup vs baseline: 1.6542x; 1.0151x over previous
//
#include <hip/hip_runtime.h>

// ---------------------------------------------------------------------------
// SelfAttentionLayer (talking-heads) on MI355X gfx950. Round 16.
// r15 (411.2 us) + idle-CU cast overlap:
//   * qkv gemm uses 192 blocks -> 64 CUs idle for its whole window. The
//     out_w/fc1_w/fc2_w casts (9.4M f32, ~14 us serial in cast_all) move into
//     the qkv dispatch as tail blocks (192..959) that run on those idle CUs.
//     Ordering safe: dispatch completes before any consumer dispatch.
//   * cast_all shrinks to qkv-cast + mix tables + ln1 (7169 blocks).
//   * all else frozen at best measured config: attn r6-loop + XCD decode
//     (133.5 us, closed), 8-phase qkv/fc1/fc2-splitK, BN=128 out-proj,
//     fc2_combine.
// ---------------------------------------------------------------------------

typedef _Float16 f16x8 __attribute__((ext_vector_type(8)));
typedef _Float16 f16x4 __attribute__((ext_vector_type(4)));
typedef _Float16 f16x2 __attribute__((ext_vector_type(2)));
typedef float f32x4 __attribute__((ext_vector_type(4)));

#define B_ 4
#define N_ 1024
#define D_ 1024
#define H_ 16
#define DH_ 64
#define FF_ 4096
#define M_ (B_ * N_)

__device__ __forceinline__ float gelu_act(float x) {
  float z = 0.7978845608028654f * (x + 0.044715f * x * x * x);
  return x / (1.0f + __expf(-2.0f * z));
}

__device__ __forceinline__ void ld_lds16(const _Float16* g, _Float16* l) {
  __builtin_amdgcn_global_load_lds((const __attribute__((address_space(1))) void*)g,
                                   (__attribute__((address_space(3))) void*)l, 16, 0, 0);
}

__device__ __forceinline__ int swz8(int i) {
  return (((i >> 2) << 1) ^ (i & 3)) & 7;
}
// S/P plane addressing (v4/v5-proven): plane p stride 1032 f16, row i (64 f16),
// col j chunk-swizzled. mix1 u16 gathers, b64 writes, b128 PV reads <=2-way.
__device__ __forceinline__ int lds_off(int p, int i, int j) {
  int ch = ((j >> 3) ^ swz8(i) ^ ((p >> 2) << 1)) & 7;
  return p * 1032 + i * 64 + (ch << 3) + (j & 7);
}

// ---------------- prep: qkv cast + mix tables + bsum zero + ln1 ----------
// blocks 0..3071: qkv_w f32->f16. block 3072: tables + bsum=0.
// blocks 3073..7168: LayerNorm1 row (b-3073) of x -> hb.
__global__ __launch_bounds__(256) void cast_all(
    const float* __restrict__ a0, _Float16* __restrict__ o0,   // qkv_w  3072*1024
    const float* __restrict__ W1, const float* __restrict__ W2,
    _Float16* __restrict__ w1f, _Float16* __restrict__ w2f,
    float* __restrict__ bsum,
    const float* __restrict__ x, const float* __restrict__ ln_w,
    const float* __restrict__ ln_b, _Float16* __restrict__ hb) {
  int b = blockIdx.x, t = threadIdx.x;
  if (b > 3072) {  // ---- LayerNorm1 branch ----
    int row = b - 3073;
    const float* xr = x + (size_t)row * D_;
    float4 v = *(const float4*)(xr + t * 4);
    float s = v.x + v.y + v.z + v.w;
    float sq = v.x * v.x + v.y * v.y + v.z * v.z + v.w * v.w;
    #pragma unroll
    for (int off = 32; off > 0; off >>= 1) {
      s += __shfl_down(s, off);
      sq += __shfl_down(sq, off);
    }
    __shared__ float red[8];
    int wave = t >> 6, lane = t & 63;
    if (lane == 0) { red[wave] = s; red[4 + wave] = sq; }
    __syncthreads();
    float ts = red[0] + red[1] + red[2] + red[3];
    float tq = red[4] + red[5] + red[6] + red[7];
    float mean = ts * (1.0f / (float)D_);
    float var = tq * (1.0f / (float)D_) - mean * mean;
    float rs = rsqrtf(var + 1e-5f);
    float4 wv = *(const float4*)(ln_w + t * 4);
    float4 bv = *(const float4*)(ln_b + t * 4);
    f16x4 o;
    o[0] = (_Float16)((v.x - mean) * rs * wv.x + bv.x);
    o[1] = (_Float16)((v.y - mean) * rs * wv.y + bv.y);
    o[2] = (_Float16)((v.z - mean) * rs * wv.z + bv.z);
    o[3] = (_Float16)((v.w - mean) * rs * wv.w + bv.w);
    *(f16x4*)(hb + (size_t)row * D_ + t * 4) = o;
    return;
  }
  if (b == 3072) {
    w1f[t] = (_Float16)W1[t];
    w2f[t] = (_Float16)W2[t];
    float4 z = {0.f, 0.f, 0.f, 0.f};
    #pragma unroll
    for (int r = 0; r < 4; r++) *(float4*)(bsum + t * 16 + r * 4) = z;
    return;
  }
  int i = (b * 256 + t) * 4;
  float4 v = *(const float4*)(a0 + i);
  f16x4 o;
  o[0] = (_Float16)v.x; o[1] = (_Float16)v.y; o[2] = (_Float16)v.z; o[3] = (_Float16)v.w;
  *(f16x4*)(o0 + i) = o;
}

// ---------------- LayerNorm (row of 1024) -> fp16 (ln2) ----------------
__global__ __launch_bounds__(256) void ln_f16(const float* __restrict__ x,
                                              const float* __restrict__ w,
                                              const float* __restrict__ b,
                                              _Float16* __restrict__ out) {
  int row = blockIdx.x;
  int tid = threadIdx.x;
  const float* xr = x + (size_t)row * D_;
  float4 v = *(const float4*)(xr + tid * 4);
  float s = v.x + v.y + v.z + v.w;
  float sq = v.x * v.x + v.y * v.y + v.z * v.z + v.w * v.w;
  #pragma unroll
  for (int off = 32; off > 0; off >>= 1) {
    s += __shfl_down(s, off);
    sq += __shfl_down(sq, off);
  }
  __shared__ float red[8];
  int wave = tid >> 6, lane = tid & 63;
  if (lane == 0) { red[wave] = s; red[4 + wave] = sq; }
  __syncthreads();
  float ts = red[0] + red[1] + red[2] + red[3];
  float tq = red[4] + red[5] + red[6] + red[7];
  float mean = ts * (1.0f / (float)D_);
  float var = tq * (1.0f / (float)D_) - mean * mean;
  float rs = rsqrtf(var + 1e-5f);
  float4 wv = *(const float4*)(w + tid * 4);
  float4 bv = *(const float4*)(b + tid * 4);
  f16x4 o;
  o[0] = (_Float16)((v.x - mean) * rs * wv.x + bv.x);
  o[1] = (_Float16)((v.y - mean) * rs * wv.y + bv.y);
  o[2] = (_Float16)((v.z - mean) * rs * wv.z + bv.z);
  o[3] = (_Float16)((v.w - mean) * rs * wv.w + bv.w);
  *(f16x4*)(out + (size_t)row * D_ + tid * 4) = o;
}

// ---------------- NT GEMM (128-tile, 2-barrier): out-proj ----------------
// SWAPXY=1: blockIdx.x indexes M-tiles (XCD owns m-strips -> A rows L2-local).
template <int EPI, int BN, int OCC, int SWAPXY>
__global__ __launch_bounds__(256, OCC) void gemm_nt(
    const _Float16* __restrict__ A, const _Float16* __restrict__ W,
    const float* __restrict__ bias, int M, int N, int K,
    _Float16* __restrict__ outB, float* __restrict__ outF,
    const float* __restrict__ res, const float* __restrict__ gamma) {
  __shared__ _Float16 As[128 * 64];
  __shared__ _Float16 Bs[BN * 64];
  int tid = threadIdx.x;
  int wave = tid >> 6, lane = tid & 63;
  int quad = lane >> 4, l16 = lane & 15;
  int wm = wave >> 1, wn = wave & 1;
  int m0 = (SWAPXY ? blockIdx.x : blockIdx.y) * 128;
  int n0 = (SWAPXY ? blockIdx.y : blockIdx.x) * BN;
  int lrow = lane >> 3, lcol = (lane & 7) * 8;
  const int NI = (BN == 128) ? 4 : 2;
  const int WN = (BN == 128) ? 64 : 32;

  f32x4 zero = {0.f, 0.f, 0.f, 0.f};
  f32x4 acc[4][NI];
  #pragma unroll
  for (int i = 0; i < 4; i++)
    #pragma unroll
    for (int j = 0; j < NI; j++) acc[i][j] = zero;

  for (int k0 = 0; k0 < K; k0 += 64) {
    __syncthreads();
    #pragma unroll
    for (int c = 0; c < 4; c++) {
      int rb = c * 32 + wave * 8;
      ld_lds16(A + (size_t)(m0 + rb + lrow) * K + k0 + lcol, As + rb * 64);
      if (BN == 128 || c < 2)
        ld_lds16(W + (size_t)(n0 + rb + lrow) * K + k0 + lcol, Bs + rb * 64);
    }
    __syncthreads();
    #pragma unroll
    for (int ks = 0; ks < 2; ks++) {
      int kk = ks * 32 + quad * 8;
      f16x8 a[4], bfr[NI];
      #pragma unroll
      for (int i = 0; i < 4; i++) a[i] = *(const f16x8*)(As + (wm * 64 + i * 16 + l16) * 64 + kk);
      #pragma unroll
      for (int i = 0; i < NI; i++) bfr[i] = *(const f16x8*)(Bs + (wn * WN + i * 16 + l16) * 64 + kk);
      #pragma unroll
      for (int mi = 0; mi < 4; mi++)
        #pragma unroll
        for (int ni = 0; ni < NI; ni++)
          acc[mi][ni] = __builtin_amdgcn_mfma_f32_16x16x32_f16(a[mi], bfr[ni], acc[mi][ni], 0, 0, 0);
    }
  }

  #pragma unroll
  for (int mi = 0; mi < 4; mi++) {
    int grow_base = m0 + wm * 64 + mi * 16 + quad * 4;
    #pragma unroll
    for (int ni = 0; ni < NI; ni++) {
      int gcol = n0 + wn * WN + ni * 16 + l16;
      float bb = bias[gcol];
      float gm = (EPI == 1) ? gamma[gcol] : 0.f;
      #pragma unroll
      for (int r = 0; r < 4; r++) {
        size_t oi = (size_t)(grow_base + r) * N + gcol;
        float c = acc[mi][ni][r] + bb;
        if (EPI == 0) {
          outB[oi] = (_Float16)c;
        } else if (EPI == 1) {
          outF[oi] = res[oi] + gm * c;
        } else {
          outB[oi] = (_Float16)gelu_act(c);
        }
      }
    }
  }
}

// ---------------- 8-phase 256x256 NT GEMM ----------------
// EPI 0: plain f16 out (qkv), 192 gemm blocks + 768 cast-tail blocks that
//   cast out_w/fc1_w/fc2_w on the 64 idle CUs (overlap; ordering safe since
//   consumers are later dispatches).
// EPI 2: gelu f16 out (fc1), grid 256.
// EPI 3: split-K partial (fc2): 64 tile-positions x 4 splits; f16 partials.
#define GPH_OPEN()                                      \
  __builtin_amdgcn_sched_barrier(0);                    \
  __builtin_amdgcn_s_barrier();                         \
  asm volatile("s_waitcnt lgkmcnt(0)" ::: "memory");    \
  __builtin_amdgcn_sched_barrier(0);                    \
  __builtin_amdgcn_s_setprio(1)

#define GPH_CLOSE()                                     \
  __builtin_amdgcn_s_setprio(0);                        \
  __builtin_amdgcn_sched_barrier(0);                    \
  __builtin_amdgcn_s_barrier()

#define GPH_CLOSE_VM(n)                                 \
  __builtin_amdgcn_s_setprio(0);                        \
  __builtin_amdgcn_sched_barrier(0);                    \
  asm volatile("s_waitcnt vmcnt(" #n ")" ::: "memory"); \
  __builtin_amdgcn_s_barrier()

#define GMFMA(MB, NB)                                                         \
  _Pragma("unroll") for (int ks = 0; ks < 2; ks++)                            \
  _Pragma("unroll") for (int mi = 0; mi < 4; mi++)                            \
  _Pragma("unroll") for (int ni = 0; ni < 2; ni++)                            \
    acc[MB + mi][NB + ni] = __builtin_amdgcn_mfma_f32_16x16x32_f16(           \
        ar[mi][ks], br[NB + ni][ks], acc[MB + mi][NB + ni], 0, 0, 0)

#define LDA(buf, MB)                                            \
  _Pragma("unroll") for (int ks = 0; ks < 2; ks++)              \
  _Pragma("unroll") for (int mi = 0; mi < 4; mi++)              \
    ar[mi][ks] = rdf(&lds[buf][0][wm][0], MB + mi, ks)

#define LDB(buf, NB)                                            \
  _Pragma("unroll") for (int ks = 0; ks < 2; ks++)              \
  _Pragma("unroll") for (int ni = 0; ni < 2; ni++)              \
    br[NB + ni][ks] = rdf(&lds[buf][1][wn >> 1][0], fbB + NB + ni, ks)

template <int EPI>
__global__ __launch_bounds__(512, 2) void gemm_nt8(
    const _Float16* __restrict__ A, const _Float16* __restrict__ W,
    const float* __restrict__ bias, int M, int N, int K,
    _Float16* __restrict__ outB, _Float16* __restrict__ outB2,
    const float* __restrict__ c0, const float* __restrict__ c1,
    const float* __restrict__ c2, _Float16* __restrict__ d0,
    _Float16* __restrict__ d1, _Float16* __restrict__ d2) {
  __shared__ _Float16 lds[2][2][2][8192];  // [buf][A=0/B=1][row-half][128*64]
  const int tid = threadIdx.x;

  if (EPI == 0 && (int)blockIdx.x >= 192) {
    // ---- cast tail: 768 blocks x 512 thr x 4 f32 x 6 sweeps = 9,437,184 ----
    // regions: out_w [0,1048576) -> d0; fc1_w [.,5242880) -> d1; fc2_w -> d2.
    const int cb = (int)blockIdx.x - 192;
    size_t g = ((size_t)cb * 512 + tid) * 4;
    #pragma unroll
    for (int sw = 0; sw < 6; sw++) {
      size_t idx = g + (size_t)sw * 1572864;
      const float* src;
      _Float16* dst;
      size_t off;
      if (idx < 1048576) { src = c0; dst = d0; off = idx; }
      else if (idx < 5242880) { src = c1; dst = d1; off = idx - 1048576; }
      else { src = c2; dst = d2; off = idx - 5242880; }
      float4 v = *(const float4*)(src + off);
      f16x4 o;
      o[0] = (_Float16)v.x; o[1] = (_Float16)v.y;
      o[2] = (_Float16)v.z; o[3] = (_Float16)v.w;
      *(f16x4*)(dst + off) = o;
    }
    return;
  }

  const int wv = tid >> 6, lane = tid & 63;
  const int quad = lane >> 4, l16 = lane & 15;
  const int wm = wv >> 2, wn = wv & 3;
  const int fbB = (wn & 1) * 4;
  const int GB = (EPI == 0) ? 192 : 256;  // gemm block count (mult of 8)
  const int wg = ((int)blockIdx.x & 7) * (GB >> 3) + ((int)blockIdx.x >> 3);
  int split = 0, kt0 = 0, m0, n0;
  if (EPI == 3) {
    split = wg >> 6;                 // 4 K-splits of 16 tiles each
    int rem = wg & 63;               // 16 m-tiles x 4 n-tiles
    m0 = (rem & 15) << 8;
    n0 = (rem >> 4) << 8;
    kt0 = split << 4;
  } else {
    m0 = (wg & 15) << 8;             // M/256 == 16 for all uses here
    n0 = (wg >> 4) << 8;
  }
  const int gc = ((lane & 7) ^ (lane >> 3)) << 3;
  const int srow = wv * 8 + (lane >> 3);

  // lt = LOCAL tile index (0..15); global K-tile = kt0 + lt (kt0 even -> same
  // buffer parity as lt).
  auto stageA = [&](int lt, int h) {
    const _Float16* g = A + (size_t)(m0 + h * 128 + srow) * K + (kt0 + lt) * 64 + gc;
    _Float16* l = &lds[lt & 1][0][h][wv * 512];
    ld_lds16(g, l);
    ld_lds16(g + (size_t)64 * K, l + 4096);
  };
  auto stageB = [&](int lt, int h) {
    const _Float16* g = W + (size_t)(n0 + h * 128 + srow) * K + (kt0 + lt) * 64 + gc;
    _Float16* l = &lds[lt & 1][1][h][wv * 512];
    ld_lds16(g, l);
    ld_lds16(g + (size_t)64 * K, l + 4096);
  };
  auto rdf = [&](const _Float16* base, int fi, int ks) -> f16x8 {
    int row = fi * 16 + l16;
    int pc = ((ks << 2) + quad) ^ (l16 & 7);
    return *(const f16x8*)(base + row * 64 + (pc << 3));
  };

  f32x4 acc[8][4];
  const f32x4 zero = {0.f, 0.f, 0.f, 0.f};
  #pragma unroll
  for (int i = 0; i < 8; i++)
    #pragma unroll
    for (int j = 0; j < 4; j++) acc[i][j] = zero;
  f16x8 ar[4][2], br[4][2];

  stageA(0, 0); stageA(0, 1); stageB(0, 0); stageB(0, 1);
  stageB(1, 0); stageB(1, 1);
  asm volatile("s_waitcnt vmcnt(4)" ::: "memory");
  __builtin_amdgcn_s_barrier();

  const int NT = 16;            // 16 local K-tiles per block
  const int ITERS = NT >> 1;    // 8
  for (int it = 0; it < ITERS - 1; ++it) {
    const int t0 = it * 2;
    LDA(0, 0); LDB(0, 0); stageA(t0 + 1, 0);
    GPH_OPEN(); GMFMA(0, 0); GPH_CLOSE();
    LDB(0, 2); stageA(t0 + 1, 1);
    GPH_OPEN(); GMFMA(0, 2); GPH_CLOSE();
    LDA(0, 4); stageB(t0 + 2, 0);
    GPH_OPEN(); GMFMA(4, 0); GPH_CLOSE();
    stageB(t0 + 2, 1);
    GPH_OPEN(); GMFMA(4, 2); GPH_CLOSE_VM(4);
    LDA(1, 0); LDB(1, 0); stageA(t0 + 2, 0);
    GPH_OPEN(); GMFMA(0, 0); GPH_CLOSE();
    LDB(1, 2); stageA(t0 + 2, 1);
    GPH_OPEN(); GMFMA(0, 2); GPH_CLOSE();
    LDA(1, 4); stageB(t0 + 3, 0);
    GPH_OPEN(); GMFMA(4, 0); GPH_CLOSE();
    stageB(t0 + 3, 1);
    GPH_OPEN(); GMFMA(4, 2); GPH_CLOSE_VM(4);
  }
  {
    LDA(0, 0); LDB(0, 0); stageA(NT - 1, 0);
    GPH_OPEN(); GMFMA(0, 0); GPH_CLOSE();
    LDB(0, 2); stageA(NT - 1, 1);
    GPH_OPEN(); GMFMA(0, 2); GPH_CLOSE();
    LDA(0, 4);
    GPH_OPEN(); GMFMA(4, 0); GPH_CLOSE();
    GPH_OPEN(); GMFMA(4, 2); GPH_CLOSE_VM(0);
    LDA(1, 0); LDB(1, 0);
    GPH_OPEN(); GMFMA(0, 0); GPH_CLOSE();
    LDB(1, 2);
    GPH_OPEN(); GMFMA(0, 2); GPH_CLOSE();
    LDA(1, 4);
    GPH_OPEN(); GMFMA(4, 0); GPH_CLOSE();
    GPH_OPEN(); GMFMA(4, 2); GPH_CLOSE();
  }

  // epilogue
  _Float16* po = outB;
  if (EPI == 3)
    po = (split < 2 ? outB : outB2) + (size_t)(split & 1) * ((size_t)M * N);
  #pragma unroll
  for (int mi = 0; mi < 8; mi++) {
    int grow = m0 + wm * 128 + mi * 16 + quad * 4;
    #pragma unroll
    for (int ni = 0; ni < 4; ni++) {
      int gcol = n0 + wn * 64 + ni * 16 + l16;
      float bb = (EPI == 3) ? 0.f : bias[gcol];
      #pragma unroll
      for (int r = 0; r < 4; r++) {
        size_t oi = (size_t)(grow + r) * N + gcol;
        float c = acc[mi][ni][r] + bb;
        po[oi] = (_Float16)(EPI == 2 ? gelu_act(c) : c);
      }
    }
  }
}

// ---------------- fc2 combine: out = x1 + gamma2*(p0+p1+p2+p3 + bias) -------
__global__ __launch_bounds__(256) void fc2_combine(
    const _Float16* __restrict__ p01, const _Float16* __restrict__ p23,
    const float* __restrict__ x1, const float* __restrict__ gamma,
    const float* __restrict__ bias, float* __restrict__ out) {
  const size_t idx = ((size_t)blockIdx.x * 256 + threadIdx.x) * 4;
  const int col = (int)(idx & (D_ - 1));
  const size_t soff = (size_t)M_ * D_;
  f16x4 a = *(const f16x4*)(p01 + idx);
  f16x4 b = *(const f16x4*)(p01 + soff + idx);
  f16x4 c = *(const f16x4*)(p23 + idx);
  f16x4 d = *(const f16x4*)(p23 + soff + idx);
  float4 xv = *(const float4*)(x1 + idx);
  float4 gv = *(const float4*)(gamma + col);
  float4 bv = *(const float4*)(bias + col);
  float4 o;
  o.x = xv.x + gv.x * ((float)a[0] + (float)b[0] + (float)c[0] + (float)d[0] + bv.x);
  o.y = xv.y + gv.y * ((float)a[1] + (float)b[1] + (float)c[1] + (float)d[1] + bv.y);
  o.z = xv.z + gv.z * ((float)a[2] + (float)b[2] + (float)c[2] + (float)d[2] + bv.z);
  o.w = xv.w + gv.w * ((float)a[3] + (float)b[3] + (float)c[3] + (float)d[3] + bv.w);
  *(float4*)(out + idx) = o;
}

// ---------------- V transpose + bsum accumulation ----------------
// vt[b][h][d][j]; also bsum[b][h*64+d] += b2[h] * sum_j V[b,h,j,d]
__global__ __launch_bounds__(256) void transpose_v(const _Float16* __restrict__ qkv,
                                                   _Float16* __restrict__ vt,
                                                   const float* __restrict__ b2,
                                                   float* __restrict__ bsum) {
  int jt = blockIdx.x;
  int h = blockIdx.y;
  int b = blockIdx.z;
  __shared__ _Float16 tl[64][68];
  int tid = threadIdx.x;
  int j0 = jt * 64;
  #pragma unroll
  for (int k = 0; k < 16; k++) {
    int idx = k * 256 + tid;
    int jr = idx >> 6, dc = idx & 63;
    tl[jr][dc] = qkv[(size_t)(b * N_ + j0 + jr) * (3 * D_) + 2 * D_ + h * 64 + dc];
  }
  __syncthreads();
  #pragma unroll
  for (int k = 0; k < 16; k++) {
    int idx = k * 256 + tid;
    int dr = idx >> 6, jc = idx & 63;
    vt[(size_t)((b * H_ + h) * DH_ + dr) * N_ + j0 + jc] = tl[jc][dr];
  }
  int d = tid & 63, jq = tid >> 6;
  float s = 0.f;
  #pragma unroll
  for (int r = 0; r < 16; r++) s += (float)tl[jq * 16 + r][d];
  atomicAdd(&bsum[b * D_ + h * 64 + d], b2[h] * s);
}

// ---------------- Talking-heads attention (r6 loop; XCD-local decode) -------
// grid (4 b, 64 i-tiles): linear id = b + 4*it -> XCD = b + 4*(it&1), so each
// XCD serves ONE batch: K+V working set 4 MB = L2-fit. Inner loop = r6.
__global__ __launch_bounds__(1024, 4) void attn_th(
    const _Float16* __restrict__ qkv, const _Float16* __restrict__ vt,
    const _Float16* __restrict__ w1f, const _Float16* __restrict__ w2f,
    const float* __restrict__ b1f, const float* __restrict__ bsum,
    _Float16* __restrict__ ob) {
  __shared__ __align__(16) _Float16 SP[2 * 16512];  // S planes | P planes
  __shared__ float lsum[272];                       // [e][i] + pad (stride 17)
  _Float16* Sp = SP;
  _Float16* Pp = SP + 16512;

  const int tid = threadIdx.x;
  const int wave = tid >> 6;
  const int lane = tid & 63;
  const int quad = lane >> 4, l16 = lane & 15;
  const int i0 = blockIdx.y * 16;
  const int b = blockIdx.x;
  const size_t bN = (size_t)b * N_;
  const f32x4 zero = {0.f, 0.f, 0.f, 0.f};

  // Q fragments (head=wave), pre-scaled by DH^-1/2 = 0.125 (exact in f16)
  f16x8 qf[2];
  #pragma unroll
  for (int ks = 0; ks < 2; ks++) {
    f16x8 q = *(const f16x8*)(qkv + (bN + i0 + l16) * 3072 + wave * 64 + ks * 32 + quad * 8);
    #pragma unroll
    for (int e = 0; e < 8; e++) q[e] = q[e] * (_Float16)0.125f;
    qf[ks] = q;
  }
  // W1 B-fragment: B[k=h][n=e] = W1[e][h]
  f16x4 w1a = *(const f16x4*)(w1f + l16 * 16 + quad * 4);
  float b1v = b1f[l16];
  f32x4 b1i = {b1v, b1v, b1v, b1v};

  const _Float16* vbase = vt + (size_t)((b * H_ + wave) * DH_ + l16) * N_ + quad * 8;

  f32x4 uacc[4];
  #pragma unroll
  for (int nt = 0; nt < 4; nt++) uacc[nt] = zero;
  float lacc = 0.f;

  // K fragments for the current tile (reloaded in place each iteration)
  f16x8 kcur[4][2];
  auto loadK = [&](int j0) {
    #pragma unroll
    for (int jb = 0; jb < 4; jb++) {
      const _Float16* kb = qkv + (bN + j0 + jb * 16 + l16) * 3072 + 1024 + wave * 64 + quad * 8;
      kcur[jb][0] = *(const f16x8*)kb;
      kcur[jb][1] = *(const f16x8*)(kb + 32);
    }
  };
  loadK(0);

  f16x8 vreg[4];  // first 32-j half of V tile, prefetched

  for (int t = 0; t < 16; t++) {
    int j0 = t * 64;
    // ---- S = (QK^T)^T for head h=wave: C[m=j][n=i] -> S plane [h][i][j]
    f32x4 sres[4];
    #pragma unroll
    for (int jb = 0; jb < 4; jb++) {
      f32x4 s = __builtin_amdgcn_mfma_f32_16x16x32_f16(kcur[jb][0], qf[0], zero, 0, 0, 0);
      sres[jb] = __builtin_amdgcn_mfma_f32_16x16x32_f16(kcur[jb][1], qf[1], s, 0, 0, 0);
    }
    #pragma unroll
    for (int jb = 0; jb < 4; jb++) {
      f16x4 sv;
      #pragma unroll
      for (int r = 0; r < 4; r++) sv[r] = (_Float16)sres[jb][r];
      *(f16x4*)(Sp + lds_off(wave, l16, jb * 16 + quad * 4)) = sv;
    }
    // ---- prefetch next K tile (kcur dead after the MFMAs above) and this
    // tile's first V half; the barrier's vmcnt(0) drain makes them resident.
    if (t < 15) loadK(j0 + 64);
    #pragma unroll
    for (int nt = 0; nt < 4; nt++)
      vreg[nt] = *(const f16x8*)(vbase + (size_t)(nt * 16) * N_ + j0);
    __syncthreads();
    // ---- mix1 (row i=wave) -> exp (unnormalized) -> P planes + l accumulate
    #pragma unroll
    for (int cg = 0; cg < 4; cg++) {
      f16x4 sf;
      #pragma unroll
      for (int t4 = 0; t4 < 4; t4++)
        sf[t4] = Sp[lds_off(quad * 4 + t4, wave, cg * 16 + l16)];
      f32x4 a = __builtin_amdgcn_mfma_f32_16x16x16f16(sf, w1a, b1i, 0, 0, 0);
      f16x4 pv;
      #pragma unroll
      for (int r = 0; r < 4; r++) {
        float e = __expf(a[r]);
        lacc += e;
        pv[r] = (_Float16)e;
      }
      *(f16x4*)(Pp + lds_off(l16, wave, cg * 16 + quad * 4)) = pv;
    }
    __syncthreads();
    // ---- PV: U_e += V @ P_e^T (e=wave): C[m=d][n=i]
    f16x8 pf0 = *(const f16x8*)(Pp + lds_off(wave, l16, quad * 8));
    f16x8 pf1 = *(const f16x8*)(Pp + lds_off(wave, l16, 32 + quad * 8));
    #pragma unroll
    for (int nt = 0; nt < 4; nt++)
      uacc[nt] = __builtin_amdgcn_mfma_f32_16x16x32_f16(vreg[nt], pf0, uacc[nt], 0, 0, 0);
    #pragma unroll
    for (int nt = 0; nt < 4; nt++) {
      f16x8 vf = *(const f16x8*)(vbase + (size_t)(nt * 16) * N_ + j0 + 32);
      uacc[nt] = __builtin_amdgcn_mfma_f32_16x16x32_f16(vf, pf1, uacc[nt], 0, 0, 0);
    }
    // no barrier: next computeS writes S planes (disjoint from P); mix1(t+1)
    // writes P only after the next barrier.
  }

  // ---------------- epilogue ----------------
  lacc += __shfl_xor(lacc, 16);
  lacc += __shfl_xor(lacc, 32);
  __syncthreads();                       // all PV reads of P done
  if (quad == 0) lsum[l16 * 17 + wave] = lacc;
  __syncthreads();
  float invl = 1.0f / lsum[wave * 17 + l16];   // (e=wave, i=l16)

  _Float16* Uf = Sp;
  #pragma unroll
  for (int nt = 0; nt < 4; nt++) {
    f16x4 u;
    #pragma unroll
    for (int r = 0; r < 4; r++) u[r] = (_Float16)(uacc[nt][r] * invl);
    *(f16x4*)(Uf + wave * 1092 + l16 * 68 + nt * 16 + quad * 4) = u;
  }
  __syncthreads();

  f16x4 w2a = *(const f16x4*)(w2f + l16 * 16 + quad * 4);
  #pragma unroll
  for (int cg = 0; cg < 4; cg++) {
    f16x4 af;
    #pragma unroll
    for (int t4 = 0; t4 < 4; t4++)
      af[t4] = Uf[(quad * 4 + t4) * 1092 + wave * 68 + cg * 16 + l16];
    f32x4 o = __builtin_amdgcn_mfma_f32_16x16x16f16(af, w2a, zero, 0, 0, 0);
    f32x4 bs = *(const f32x4*)(bsum + b * D_ + l16 * 64 + cg * 16 + quad * 4);
    f16x4 ov;
    #pragma unroll
    for (int r = 0; r < 4; r++) ov[r] = (_Float16)(o[r] + bs[r]);
    *(f16x4*)(ob + (bN + i0 + wave) * D_ + l16 * 64 + cg * 16 + quad * 4) = ov;
  }
}

// ---------------------------------------------------------------------------
extern "C" void kernel_launch(void* const* d_in, const int* in_sizes, int n_in,
                              void* d_out, int out_size, void* d_ws, size_t ws_size,
                              hipStream_t stream) {
  const float* x      = (const float*)d_in[0];
  const float* ln1_w  = (const float*)d_in[1];
  const float* ln1_b  = (const float*)d_in[2];
  const float* qkv_w  = (const float*)d_in[3];
  const float* qkv_b  = (const float*)d_in[4];
  const float* plw    = (const float*)d_in[5];
  const float* plb    = (const float*)d_in[6];
  const float* pww    = (const float*)d_in[7];
  const float* pwb    = (const float*)d_in[8];
  const float* out_w  = (const float*)d_in[9];
  const float* out_b  = (const float*)d_in[10];
  const float* gamma1 = (const float*)d_in[11];
  const float* ln2_w  = (const float*)d_in[12];
  const float* ln2_b  = (const float*)d_in[13];
  const float* fc1_w  = (const float*)d_in[14];
  const float* fc1_b  = (const float*)d_in[15];
  const float* fc2_w  = (const float*)d_in[16];
  const float* fc2_b  = (const float*)d_in[17];
  const float* gamma2 = (const float*)d_in[18];
  float* out = (float*)d_out;

  char* ws = (char*)d_ws;
  _Float16* wq   = (_Float16*)(ws + 0);          // 6291456 B
  _Float16* wo   = (_Float16*)(ws + 6291456);    // 2097152 B
  _Float16* wf1  = (_Float16*)(ws + 8388608);    // 8388608 B (clean fc1 weights)
  _Float16* wf2  = (_Float16*)(ws + 16777216);   // 8388608 B
  float*    x1   = (float*)   (ws + 25165824);   // 16777216 B (first 17.4 KB host
                                                 //  mix tables/bsum during attn)
  _Float16* ob   = (_Float16*)(ws + 41943040);   // 8388608 B
  _Float16* hb   = (_Float16*)(ws + 50331648);   // 8388608 B
  _Float16* qkvb = (_Float16*)(ws + 58720256);   // 25165824 B
  _Float16* vtb  = (_Float16*)(ws + 83886080);   // 8388608 B
  _Float16* fb   = (_Float16*)(ws + 58720256);   // 33554432 B, aliases qkvb+vtb (dead by then)
  _Float16* w1f  = (_Float16*)(ws + 25165824);          // 512 B
  _Float16* w2f  = (_Float16*)(ws + 25165824 + 512);    // 512 B
  float*    bsum = (float*)   (ws + 25165824 + 1024);   // 16384 B
  // fc2 split-K partials (live only during fc2 gemm + combine):
  _Float16* p01  = (_Float16*)(ws + 0);          // 16777216 B over wq/wo/wf1 (dead)
  _Float16* p23  = (_Float16*)(ws + 41943040);   // 16777216 B over ob/hb (dead)
  if (ws_size < 92274688) return;

  cast_all<<<7169, 256, 0, stream>>>(qkv_w, wq, plw, pww, w1f, w2f, bsum,
                                     x, ln1_w, ln1_b, hb);

  // qkv gemm (192 blocks) + out_w/fc1_w/fc2_w cast tail on the 64 idle CUs
  gemm_nt8<0><<<960, 512, 0, stream>>>(hb, wq, qkv_b, M_, 3 * D_, D_, qkvb, nullptr,
                                       out_w, fc1_w, fc2_w, wo, wf1, wf2);
  transpose_v<<<dim3(16, 16, 4), 256, 0, stream>>>(qkvb, vtb, pwb, bsum);
  attn_th<<<dim3(4, 64), 1024, 0, stream>>>(qkvb, vtb, w1f, w2f, plb, bsum, ob);
  gemm_nt<1, 128, 3, 1><<<dim3(32, 8), 256, 0, stream>>>(ob, wo, out_b, M_, D_, D_, nullptr, x1, x, gamma1);

  ln_f16<<<4096, 256, 0, stream>>>(x1, ln2_w, ln2_b, hb);
  gemm_nt8<2><<<256, 512, 0, stream>>>(hb, wf1, fc1_b, M_, FF_, D_, fb, nullptr,
                                       nullptr, nullptr, nullptr, nullptr, nullptr, nullptr);
  gemm_nt8<3><<<256, 512, 0, stream>>>(fb, wf2, fc2_b, M_, D_, FF_, p01, p23,
                                       nullptr, nullptr, nullptr, nullptr, nullptr, nullptr);
  fc2_combine<<<4096, 256, 0, stream>>>(p01, p23, x1, gamma2, fc2_b, out);
}